// Round 2
// baseline (485.222 us; speedup 1.0000x reference)
//
#include <hip/hip_runtime.h>
#include <math.h>

#define NB 4
#define NV 512
#define NF 64
#define NT 16
#define NE 16384

// ---------------- workspace layout (float offsets) ----------------
// Overlapped lifetimes: Xt shares XHAT, ST shares TX1, sigT shares TX2.
#define TX0_OFF    0u          // (B*T,N,F)  2097152
#define TX1_OFF    2097152u    // 2097152  (also ST until k_wS)
#define TX2_OFF    4194304u    // 2097152  (also sigT until k_gemm_s)
#define XHAT_OFF   6291456u    // 2097152  (also Xt until k_spat)
#define ST_OFF     TX1_OFF
#define SIGT_OFF   TX2_OFF
#define XT_OFF     XHAT_OFF
#define BST_OFF    8388608u    // bs transposed 262144
#define ET_OFF     8650752u    // (B,16,16) 1024
#define PART_OFF   8651776u    // lhs1 partials 4*8*1024 = 32768
#define RHST_OFF   8684544u    // rhs_t (B,N,T) 32768
#define LHSS_OFF   8717312u    // lhs_s (B,N,T) 32768
#define RHSSN_OFF  8750080u    // rhs_s stored (B,N,T) 32768
#define DIAGS_OFF  8782848u    // (B,N) 2048
#define WSATT_OFF  8784896u    // wS (B,E) 65536
#define CSRW_OFF   8850432u    // 16384
#define WTT_OFF    8866816u    // 12288
#define WRT_OFF    8879104u    // 4096
#define DIS_OFF    8883200u    // 512
#define FEND       8883712u    // floats; ints live after this (~203 KB)

// ============ graph prep ============
__global__ void k_deg(const int* __restrict__ row, int* __restrict__ deg) {
    int e = blockIdx.x * 256 + threadIdx.x;
    if (e < NE) atomicAdd(&deg[row[e]], 1);
}

__global__ void k_scan(const int* __restrict__ deg, float* __restrict__ dis,
                       int* __restrict__ row_start, int* __restrict__ cursor) {
    __shared__ int sc[512];
    int tid = threadIdx.x;
    int d = deg[tid];
    dis[tid] = d > 0 ? 1.0f / sqrtf((float)d) : 0.0f;
    sc[tid] = d;
    __syncthreads();
    for (int off = 1; off < 512; off <<= 1) {
        int v = sc[tid];
        int add = (tid >= off) ? sc[tid - off] : 0;
        __syncthreads();
        sc[tid] = v + add;
        __syncthreads();
    }
    int incl = sc[tid];
    int excl = incl - d;
    row_start[tid] = excl;
    cursor[tid] = excl;
    if (tid == 511) row_start[512] = incl;
}

__global__ void k_fill(const int* __restrict__ row, int* __restrict__ cursor,
                       int* __restrict__ eid) {
    int e = blockIdx.x * 256 + threadIdx.x;
    if (e < NE) { int pos = atomicAdd(&cursor[row[e]], 1); eid[pos] = e; }
}

// sort each row slice by edge id (deterministic CSR), emit col/row/weight
__global__ void k_csr(const int* __restrict__ row_start, int* __restrict__ eid,
                      const int* __restrict__ colA, const float* __restrict__ dis,
                      int* __restrict__ csr_col, int* __restrict__ csr_row,
                      float* __restrict__ csr_w) {
    int n = blockIdx.x * 64 + threadIdx.x;
    int s = row_start[n], e2 = row_start[n + 1];
    for (int a = s + 1; a < e2; ++a) {
        int key = eid[a]; int b = a - 1;
        while (b >= s && eid[b] > key) { eid[b + 1] = eid[b]; --b; }
        eid[b + 1] = key;
    }
    float dn = dis[n];
    for (int p = s; p < e2; ++p) {
        int e = eid[p]; int c = colA[e];
        csr_col[p] = c; csr_row[p] = n;
        csr_w[p] = -dn * dis[c];
    }
}

// ============ weight transposes ============
__global__ void k_wprep(const float* __restrict__ Wt, const float* __restrict__ Wr,
                        float* __restrict__ WtT, float* __restrict__ WrT) {
    int idx = blockIdx.x * 256 + threadIdx.x;
    if (idx < 12288) {
        int o = idx & 63, gd = idx >> 6;      // gd = g*3+dt
        int g = gd / 3, dt = gd - g * 3;
        WtT[idx] = Wt[(o * 64 + g) * 3 + dt];
    } else if (idx < 16384) {
        int i2 = idx - 12288;
        int o = i2 & 63, f = i2 >> 6;
        WrT[i2] = Wr[o * 64 + f];
    }
}

__global__ void k_bst(const float* __restrict__ bs, float* __restrict__ bsT) {
    __shared__ float tile[64][65];
    int r0 = blockIdx.y * 64, c0 = blockIdx.x * 64;
    int c = threadIdx.x & 63, rq = threadIdx.x >> 6;
    for (int k = 0; k < 16; ++k) {
        int r = rq * 16 + k;
        tile[r][c] = bs[(r0 + r) * 512 + c0 + c];
    }
    __syncthreads();
    int r2 = threadIdx.x & 63;
    for (int k = 0; k < 16; ++k) {
        int c2 = rq * 16 + k;
        bsT[(size_t)(c0 + c2) * 512 + r0 + r2] = tile[r2][c2];
    }
}

// ============ temporal attention ============
// partial lhs1[b][g][f*16+t] over 64-n chunk
__global__ void k_lhs1_partial(const float* __restrict__ X, const float* __restrict__ U1,
                               float* __restrict__ part) {
    int b = blockIdx.x >> 3, g = blockIdx.x & 7;
    int tid = threadIdx.x;
    float acc[4] = {0.f, 0.f, 0.f, 0.f};
    const float* Xb = X + (size_t)b * NV * 1024;
    int n0 = g * 64;
    for (int nn = 0; nn < 64; ++nn) {
        int n = n0 + nn;
        float u = U1[n];
        const float* xp = Xb + (size_t)n * 1024;
#pragma unroll
        for (int k = 0; k < 4; ++k) acc[k] += xp[tid + 256 * k] * u;
    }
#pragma unroll
    for (int k = 0; k < 4; ++k) part[(size_t)(b * 8 + g) * 1024 + tid + 256 * k] = acc[k];
}

// rhs_t[b][n][t] = sum_f U3[f]*X[b,n,f,t]
__global__ void k_rhs_t(const float* __restrict__ X, const float* __restrict__ U3,
                        float* __restrict__ rhs) {
    int gid = blockIdx.x * 256 + threadIdx.x;
    int t = gid & 15, n = (gid >> 4) & 511, b = gid >> 13;
    const float* xp = X + ((size_t)(b * 512 + n)) * 1024 + t;
    float a = 0.f;
#pragma unroll
    for (int f = 0; f < 64; ++f) a += U3[f] * xp[f * 16];
    rhs[gid] = a;
}

__global__ void k_temporal(const float* __restrict__ part, const float* __restrict__ rhs_g,
                           const float* __restrict__ U2, const float* __restrict__ be,
                           const float* __restrict__ Ve, float* __restrict__ Et) {
    __shared__ float lhs1[1024];
    __shared__ float rhsL[8192];
    __shared__ float M[1024];
    __shared__ float Esig[256];
    __shared__ float Et0[256];
    __shared__ float red[32];
    int b = blockIdx.x, tid = threadIdx.x;
#pragma unroll
    for (int k = 0; k < 4; ++k) {
        int idx = tid + 256 * k;
        float s = 0.f;
        for (int g = 0; g < 8; ++g) s += part[(size_t)(b * 8 + g) * 1024 + idx];
        lhs1[idx] = s;
    }
    for (int k = 0; k < 32; ++k) rhsL[tid + 256 * k] = rhs_g[(size_t)b * 8192 + tid + 256 * k];
    __syncthreads();
    // M[f*16+t] = sum_n U2[f*512+n]*rhsL[n*16+t]
    {
        float acc[4] = {0.f, 0.f, 0.f, 0.f};
        int fA[4], tA[4];
#pragma unroll
        for (int k = 0; k < 4; ++k) { int idx = tid + 256 * k; fA[k] = idx >> 4; tA[k] = idx & 15; }
        for (int n = 0; n < 512; ++n) {
#pragma unroll
            for (int k = 0; k < 4; ++k) acc[k] += U2[fA[k] * 512 + n] * rhsL[n * 16 + tA[k]];
        }
#pragma unroll
        for (int k = 0; k < 4; ++k) M[tid + 256 * k] = acc[k];
    }
    __syncthreads();
    {
        int t1 = tid >> 4, t2 = tid & 15;
        float s = 0.f;
        for (int f = 0; f < 64; ++f) s += lhs1[f * 16 + t1] * M[f * 16 + t2];
        s += be[t1 * 16 + t2];
        Esig[tid] = 1.f / (1.f + expf(-s));
    }
    __syncthreads();
    {
        int t1 = tid >> 4, t2 = tid & 15;
        float s = 0.f;
        for (int k = 0; k < 16; ++k) s += Ve[t1 * 16 + k] * Esig[k * 16 + t2];
        Et0[tid] = s;
    }
    __syncthreads();
    if (tid < 16) {
        float m = -1e30f;
        for (int k = 0; k < 16; ++k) m = fmaxf(m, Et0[k * 16 + tid]);
        float s = 0.f;
        for (int k = 0; k < 16; ++k) s += expf(Et0[k * 16 + tid] - m);
        red[tid] = m; red[16 + tid] = 1.f / s;
    }
    __syncthreads();
    {
        int t2 = tid & 15;
        Et[b * 256 + tid] = expf(Et0[tid] - red[t2]) * red[16 + t2];
    }
}

// ============ Xt = X @ Et ============
__global__ void k_xt(const float* __restrict__ X, const float* __restrict__ Et,
                     float* __restrict__ Xt) {
    __shared__ float EtL[256];
    int tid = threadIdx.x;
    int b = blockIdx.x >> 7;          // 128 blocks per batch
    size_t base = (size_t)blockIdx.x * 256 + tid;   // (b*32768 + nf)
    EtL[tid] = Et[b * 256 + tid];
    __syncthreads();
    const float4* xp = (const float4*)(X + base * 16);
    float4 a0 = xp[0], a1 = xp[1], a2 = xp[2], a3 = xp[3];
    float x[16] = {a0.x, a0.y, a0.z, a0.w, a1.x, a1.y, a1.z, a1.w,
                   a2.x, a2.y, a2.z, a2.w, a3.x, a3.y, a3.z, a3.w};
    float o[16];
#pragma unroll
    for (int t = 0; t < 16; ++t) {
        float s = 0.f;
#pragma unroll
        for (int tp = 0; tp < 16; ++tp) s += x[tp] * EtL[tp * 16 + t];
        o[t] = s;
    }
    float4* op = (float4*)(Xt + base * 16);
    op[0] = make_float4(o[0], o[1], o[2], o[3]);
    op[1] = make_float4(o[4], o[5], o[6], o[7]);
    op[2] = make_float4(o[8], o[9], o[10], o[11]);
    op[3] = make_float4(o[12], o[13], o[14], o[15]);
}

// ============ spatial attention small parts ============
__global__ void k_spat(const float* __restrict__ Xt, const float* __restrict__ Ws1,
                       const float* __restrict__ Ws2, const float* __restrict__ Ws3,
                       float* __restrict__ lhs_s, float* __restrict__ rhs_sn) {
    __shared__ float xl[1024];
    __shared__ float l1[64];
    int bn = blockIdx.x, tid = threadIdx.x;
    const float* xp = Xt + (size_t)bn * 1024;
    for (int k = 0; k < 16; ++k) xl[tid + 64 * k] = xp[tid + 64 * k];
    __syncthreads();
    float s = 0.f;
#pragma unroll
    for (int t = 0; t < 16; ++t) s += xl[tid * 16 + t] * Ws1[t];
    l1[tid] = s;
    __syncthreads();
    if (tid < 16) {
        float a = 0.f;
        for (int f = 0; f < 64; ++f) a += l1[f] * Ws2[f * 16 + tid];
        lhs_s[(size_t)bn * 16 + tid] = a;
    } else if (tid < 32) {
        int t = tid - 16;
        float a = 0.f;
        for (int f = 0; f < 64; ++f) a += Ws3[f] * xl[f * 16 + t];
        rhs_sn[(size_t)bn * 16 + t] = a;
    }
}

// sigT[b][j][k] = sigmoid(lhs_s[b,k,:]·rhs_sn[b,j,:] + bs[k,j])
// grid: B*N*N/256 = 4096 blocks (b = gid>>18)
__global__ void k_sigT(const float* __restrict__ lhs_s, const float* __restrict__ rhs_sn,
                       const float* __restrict__ bsT, float* __restrict__ sigT) {
    int gid = blockIdx.x * 256 + threadIdx.x;
    int k = gid & 511, j = (gid >> 9) & 511, b = gid >> 18;
    const float4* lp = (const float4*)(lhs_s + (size_t)(b * 512 + k) * 16);
    const float4* rp = (const float4*)(rhs_sn + (size_t)(b * 512 + j) * 16);
    float s = 0.f;
#pragma unroll
    for (int q = 0; q < 4; ++q) {
        float4 a = lp[q], c = rp[q];
        s += a.x * c.x + a.y * c.y + a.z * c.z + a.w * c.w;
    }
    s += bsT[(size_t)j * 512 + k];
    sigT[gid] = 1.f / (1.f + expf(-s));
}

// S0T[b][j][i] = sum_k sigT[b][j][k] * Vs[i][k]
__global__ __launch_bounds__(256) void k_gemm_s(const float* __restrict__ sigT,
                                                const float* __restrict__ Vs,
                                                float* __restrict__ S0T) {
    __shared__ float As[64 * 33];
    __shared__ float Bs[64 * 33];
    int bI = blockIdx.x, bJ = blockIdx.y, b = blockIdx.z;
    int tid = threadIdx.x, tx = tid & 15, ty = tid >> 4;
    float acc[4][4] = {};
    const float* Ab = sigT + ((size_t)b * 512 + bJ * 64) * 512;
    const float* Bb = Vs + (size_t)bI * 64 * 512;
    for (int k0 = 0; k0 < 512; k0 += 32) {
#pragma unroll
        for (int p = 0; p < 2; ++p) {
            int idx = tid + 256 * p;
            int row = idx >> 3, kk = (idx & 7) * 4;
            float4 a = *(const float4*)(Ab + (size_t)row * 512 + k0 + kk);
            As[row * 33 + kk] = a.x; As[row * 33 + kk + 1] = a.y;
            As[row * 33 + kk + 2] = a.z; As[row * 33 + kk + 3] = a.w;
            float4 v = *(const float4*)(Bb + (size_t)row * 512 + k0 + kk);
            Bs[row * 33 + kk] = v.x; Bs[row * 33 + kk + 1] = v.y;
            Bs[row * 33 + kk + 2] = v.z; Bs[row * 33 + kk + 3] = v.w;
        }
        __syncthreads();
#pragma unroll
        for (int kk = 0; kk < 32; ++kk) {
            float a[4], bb[4];
#pragma unroll
            for (int q = 0; q < 4; ++q) a[q] = As[(ty * 4 + q) * 33 + kk];
#pragma unroll
            for (int q = 0; q < 4; ++q) bb[q] = Bs[(tx * 4 + q) * 33 + kk];
#pragma unroll
            for (int y = 0; y < 4; ++y)
#pragma unroll
                for (int x = 0; x < 4; ++x) acc[y][x] += a[y] * bb[x];
        }
        __syncthreads();
    }
    float* Cb = S0T + ((size_t)b * 512 + bJ * 64) * 512 + bI * 64;
#pragma unroll
    for (int y = 0; y < 4; ++y) {
        int j = ty * 4 + y;
        *(float4*)(Cb + (size_t)j * 512 + tx * 4) =
            make_float4(acc[y][0], acc[y][1], acc[y][2], acc[y][3]);
    }
}

// softmax over i (contiguous) in-place; extract diagonal
__global__ void k_softmax_s(float* __restrict__ ST, float* __restrict__ diagS) {
    __shared__ float red[4];
    int bj = blockIdx.x;
    int b = bj >> 9, j = bj & 511;
    float* row = ST + (size_t)bj * 512;
    int tid = threadIdx.x;
    float v0 = row[tid], v1 = row[tid + 256];
    float m = fmaxf(v0, v1);
    for (int off = 32; off; off >>= 1) m = fmaxf(m, __shfl_xor(m, off));
    if ((tid & 63) == 0) red[tid >> 6] = m;
    __syncthreads();
    m = fmaxf(fmaxf(red[0], red[1]), fmaxf(red[2], red[3]));
    __syncthreads();
    float e0 = expf(v0 - m), e1 = expf(v1 - m);
    float s = e0 + e1;
    for (int off = 32; off; off >>= 1) s += __shfl_xor(s, off);
    if ((tid & 63) == 0) red[tid >> 6] = s;
    __syncthreads();
    s = red[0] + red[1] + red[2] + red[3];
    float inv = 1.f / s;
    float r0 = e0 * inv, r1 = e1 * inv;
    row[tid] = r0;
    row[tid + 256] = r1;
    if (j < 256) { if (tid == j) diagS[b * 512 + j] = r0; }
    else { if (tid == j - 256) diagS[b * 512 + j] = r1; }
}

// wS[b][pos] = csr_w[pos] * S[b, row, col] = csr_w * ST[b][col][row]
__global__ void k_wS(const int* __restrict__ csr_col, const int* __restrict__ csr_row,
                     const float* __restrict__ csr_w, const float* __restrict__ ST,
                     float* __restrict__ wS) {
    int gid = blockIdx.x * 256 + threadIdx.x;
    int pos = gid & (NE - 1), b = gid >> 14;
    int c = csr_col[pos], r = csr_row[pos];
    wS[gid] = csr_w[pos] * ST[((size_t)(b * 512 + c)) * 512 + r];
}

// Tx0[bt][n][f] = diagS[b,n]*X[b,n,f,t]
__global__ void k_tx0(const float* __restrict__ X, const float* __restrict__ diagS,
                      float* __restrict__ Tx0) {
    __shared__ float xl[1088];   // [f][t] padded 17
    int bn = blockIdx.x;
    int b = bn >> 9, n = bn & 511;
    int tid = threadIdx.x;
    const float* xp = X + (size_t)bn * 1024;
#pragma unroll
    for (int k = 0; k < 4; ++k) {
        int idx = tid + 256 * k;
        xl[(idx >> 4) * 17 + (idx & 15)] = xp[idx];
    }
    float s = diagS[bn];
    __syncthreads();
    int f = tid & 63, tg = tid >> 6;
#pragma unroll
    for (int tt = 0; tt < 4; ++tt) {
        int t = tg * 4 + tt;
        Tx0[(((size_t)b * 16 + t) * 512 + n) * 64 + f] = xl[f * 17 + t] * s;
    }
}

__global__ void k_prop1(const float* __restrict__ Tx0, const float* __restrict__ wS,
                        const int* __restrict__ csr_col, const int* __restrict__ row_start,
                        float* __restrict__ Tx1) {
    int blk = blockIdx.x;
    int i = blk & 511, bt = blk >> 9, b = blk >> 13;
    int f = threadIdx.x;
    int s = row_start[i], e2 = row_start[i + 1];
    const float* base = Tx0 + (size_t)bt * 512 * 64;
    const float* wb = wS + (size_t)b * NE;
    float acc = 0.f;
    for (int p = s; p < e2; ++p)
        acc += wb[p] * base[(size_t)csr_col[p] * 64 + f];
    Tx1[((size_t)bt * 512 + i) * 64 + f] = acc;
}

__global__ void k_prop2(const float* __restrict__ Tx1, const float* __restrict__ Tx0,
                        const float* __restrict__ csr_w, const int* __restrict__ csr_col,
                        const int* __restrict__ row_start, float* __restrict__ Tx2) {
    int blk = blockIdx.x;
    int i = blk & 511, bt = blk >> 9;
    int f = threadIdx.x;
    int s = row_start[i], e2 = row_start[i + 1];
    const float* base = Tx1 + (size_t)bt * 512 * 64;
    float acc = 0.f;
    for (int p = s; p < e2; ++p)
        acc += csr_w[p] * base[(size_t)csr_col[p] * 64 + f];
    size_t oi = ((size_t)bt * 512 + i) * 64 + f;
    Tx2[oi] = 2.f * acc - Tx0[oi];
}

// X_hat = relu(Tx0@W0 + Tx1@W1 + Tx2@W2 + b_cheb)
__global__ __launch_bounds__(256) void k_cheb(const float* __restrict__ Tx0,
                                              const float* __restrict__ Tx1,
                                              const float* __restrict__ Tx2,
                                              const float* __restrict__ Wc,
                                              const float* __restrict__ bc,
                                              float* __restrict__ Xh) {
    __shared__ float Wl[3 * 4096];
    __shared__ float t0s[1024], t1s[1024], t2s[1024];
    __shared__ float bcl[64];
    int tid = threadIdx.x;
#pragma unroll
    for (int k = 0; k < 48; ++k) Wl[tid + 256 * k] = Wc[tid + 256 * k];
    if (tid < 64) bcl[tid] = bc[tid];
    int g = tid & 63, r0 = tid >> 6;
    size_t rbase = (size_t)blockIdx.x * 64;
    float acc[16];
#pragma unroll
    for (int k = 0; k < 16; ++k) acc[k] = 0.f;
    for (int f0 = 0; f0 < 64; f0 += 16) {
        __syncthreads();
#pragma unroll
        for (int p = 0; p < 4; ++p) {
            int idx = tid + 256 * p;
            int row = idx >> 4, ff = idx & 15;
            size_t gi = (rbase + row) * 64 + f0 + ff;
            t0s[idx] = Tx0[gi];
            t1s[idx] = Tx1[gi];
            t2s[idx] = Tx2[gi];
        }
        __syncthreads();
        for (int ff = 0; ff < 16; ++ff) {
            int f = f0 + ff;
            float w0 = Wl[f * 64 + g], w1 = Wl[4096 + f * 64 + g], w2 = Wl[8192 + f * 64 + g];
#pragma unroll
            for (int k = 0; k < 16; ++k) {
                int row = r0 + 4 * k;
                acc[k] += t0s[row * 16 + ff] * w0 + t1s[row * 16 + ff] * w1 + t2s[row * 16 + ff] * w2;
            }
        }
    }
#pragma unroll
    for (int k = 0; k < 16; ++k) {
        size_t r = rbase + r0 + 4 * k;
        Xh[r * 64 + g] = fmaxf(acc[k] + bcl[g], 0.f);
    }
}

// fused time-conv + residual conv + relu + LayerNorm + output transpose
__global__ __launch_bounds__(256) void k_out(const float* __restrict__ X,
                                             const float* __restrict__ Xh,
                                             const float* __restrict__ WtT,
                                             const float* __restrict__ WrT,
                                             const float* __restrict__ bt,
                                             const float* __restrict__ br,
                                             const float* __restrict__ gamma,
                                             const float* __restrict__ beta,
                                             float* __restrict__ out) {
    __shared__ float Wl[12288];   // [(g*3+dt)*64+o]
    __shared__ float xh[1024];    // [t][g]
    __shared__ float xl[1088];    // [f][t] padded 17
    __shared__ float z[1024];     // [t][o]
    int bn = blockIdx.x;
    int b = bn >> 9, n = bn & 511;
    int tid = threadIdx.x;
#pragma unroll
    for (int k = 0; k < 48; ++k) Wl[tid + 256 * k] = WtT[tid + 256 * k];
#pragma unroll
    for (int k = 0; k < 4; ++k) {
        int idx = tid + 256 * k;
        xl[(idx >> 4) * 17 + (idx & 15)] = X[(size_t)bn * 1024 + idx];
    }
#pragma unroll
    for (int k = 0; k < 4; ++k) {
        int idx = tid + 256 * k;
        int t = idx >> 6, g = idx & 63;
        xh[idx] = Xh[(((size_t)b * 16 + t) * 512 + n) * 64 + g];
    }
    __syncthreads();
    int o = tid & 63, tg = tid >> 6;
    float bto = bt[o], bro = br[o], go = gamma[o], bo = beta[o];
    for (int tt = 0; tt < 4; ++tt) {
        int t = tg * 4 + tt;
        float ct = bto;
#pragma unroll
        for (int dt = 0; dt < 3; ++dt) {
            int ts = t + dt - 1;
            if (ts < 0 || ts > 15) continue;
            for (int g = 0; g < 64; ++g)
                ct += xh[ts * 64 + g] * Wl[(g * 3 + dt) * 64 + o];
        }
        float cr = bro;
        for (int f = 0; f < 64; ++f) cr += xl[f * 17 + t] * WrT[f * 64 + o];
        float zv = fmaxf(ct + cr, 0.f);
        float s = zv, sq = zv * zv;
        for (int off = 32; off; off >>= 1) {
            s += __shfl_xor(s, off);
            sq += __shfl_xor(sq, off);
        }
        float mu = s * (1.f / 64.f);
        float var = sq * (1.f / 64.f) - mu * mu;
        float zn = (zv - mu) * rsqrtf(var + 1e-5f) * go + bo;
        z[t * 64 + o] = zn;
    }
    __syncthreads();
#pragma unroll
    for (int k = 0; k < 4; ++k) {
        int i = tid + 256 * k;
        out[(size_t)bn * 1024 + i] = z[(i & 15) * 64 + (i >> 4)];
    }
}

extern "C" void kernel_launch(void* const* d_in, const int* in_sizes, int n_in,
                              void* d_out, int out_size, void* d_ws, size_t ws_size,
                              hipStream_t stream) {
    const float* X     = (const float*)d_in[0];
    const int*   ei    = (const int*)d_in[1];
    const float* U1    = (const float*)d_in[2];
    const float* U2    = (const float*)d_in[3];
    const float* U3    = (const float*)d_in[4];
    const float* be    = (const float*)d_in[5];
    const float* Ve    = (const float*)d_in[6];
    const float* Ws1   = (const float*)d_in[7];
    const float* Ws2   = (const float*)d_in[8];
    const float* Ws3   = (const float*)d_in[9];
    const float* bs    = (const float*)d_in[10];
    const float* Vs    = (const float*)d_in[11];
    const float* Wc    = (const float*)d_in[12];
    const float* bc    = (const float*)d_in[13];
    const float* Wt    = (const float*)d_in[14];
    const float* bt    = (const float*)d_in[15];
    const float* Wr    = (const float*)d_in[16];
    const float* br    = (const float*)d_in[17];
    const float* gamma = (const float*)d_in[18];
    const float* beta  = (const float*)d_in[19];

    float* ws = (float*)d_ws;
    float* Tx0    = ws + TX0_OFF;
    float* Tx1    = ws + TX1_OFF;
    float* Tx2    = ws + TX2_OFF;
    float* Xh     = ws + XHAT_OFF;
    float* Xt     = ws + XT_OFF;     // shares XHAT (dead before k_cheb)
    float* ST     = ws + ST_OFF;     // shares TX1 (dead before k_prop1)
    float* sigT   = ws + SIGT_OFF;   // shares TX2 (dead before k_prop2)
    float* bsT    = ws + BST_OFF;
    float* Et     = ws + ET_OFF;
    float* part   = ws + PART_OFF;
    float* rhs_t  = ws + RHST_OFF;
    float* lhs_s  = ws + LHSS_OFF;
    float* rhs_sn = ws + RHSSN_OFF;
    float* diagS  = ws + DIAGS_OFF;
    float* wS     = ws + WSATT_OFF;
    float* csr_w  = ws + CSRW_OFF;
    float* WtT    = ws + WTT_OFF;
    float* WrT    = ws + WRT_OFF;
    float* dis    = ws + DIS_OFF;

    int* ib        = (int*)(ws + FEND);
    int* deg       = ib;
    int* row_start = ib + 512;
    int* cursor    = ib + 1025;
    int* csr_col   = ib + 1537;
    int* csr_row   = csr_col + NE;
    int* eid       = csr_row + NE;

    // graph prep (independent)
    hipMemsetAsync(deg, 0, 512 * sizeof(int), stream);
    k_deg<<<64, 256, 0, stream>>>(ei, deg);
    k_scan<<<1, 512, 0, stream>>>(deg, dis, row_start, cursor);
    k_fill<<<64, 256, 0, stream>>>(ei, cursor, eid);
    k_csr<<<8, 64, 0, stream>>>(row_start, eid, ei + NE, dis, csr_col, csr_row, csr_w);

    // weight transposes (independent)
    k_wprep<<<64, 256, 0, stream>>>(Wt, Wr, WtT, WrT);
    k_bst<<<dim3(8, 8), 256, 0, stream>>>(bs, bsT);

    // temporal attention
    k_lhs1_partial<<<32, 256, 0, stream>>>(X, U1, part);
    k_rhs_t<<<128, 256, 0, stream>>>(X, U3, rhs_t);
    k_temporal<<<4, 256, 0, stream>>>(part, rhs_t, U2, be, Ve, Et);
    k_xt<<<512, 256, 0, stream>>>(X, Et, Xt);

    // spatial attention
    k_spat<<<2048, 64, 0, stream>>>(Xt, Ws1, Ws2, Ws3, lhs_s, rhs_sn);
    k_sigT<<<4096, 256, 0, stream>>>(lhs_s, rhs_sn, bsT, sigT);   // B*N*N/256
    k_gemm_s<<<dim3(8, 8, 4), 256, 0, stream>>>(sigT, Vs, ST);
    k_softmax_s<<<2048, 256, 0, stream>>>(ST, diagS);
    k_wS<<<256, 256, 0, stream>>>(csr_col, csr_row, csr_w, ST, wS);

    // chebyshev conv
    k_tx0<<<2048, 256, 0, stream>>>(X, diagS, Tx0);
    k_prop1<<<32768, 64, 0, stream>>>(Tx0, wS, csr_col, row_start, Tx1);
    k_prop2<<<32768, 64, 0, stream>>>(Tx1, Tx0, csr_w, csr_col, row_start, Tx2);
    k_cheb<<<512, 256, 0, stream>>>(Tx0, Tx1, Tx2, Wc, bc, Xh);

    // time conv + residual + LN + transpose
    k_out<<<2048, 256, 0, stream>>>(X, Xh, WtT, WrT, bt, br, gamma, beta, (float*)d_out);
}

// Round 3
// 311.583 us; speedup vs baseline: 1.5573x; 1.5573x over previous
//
#include <hip/hip_runtime.h>
#include <math.h>

#define NB 4
#define NV 512
#define NF 64
#define NT 16
#define NE 16384

// ---------------- workspace layout (float offsets) ----------------
// Overlapped lifetimes: Xt shares XHAT, ST shares TX1, sigT shares TX2.
#define TX0_OFF    0u          // (B*T,N,F)  2097152
#define TX1_OFF    2097152u    // 2097152  (also ST until k_wS)
#define TX2_OFF    4194304u    // 2097152  (also sigT until k_gemm_s)
#define XHAT_OFF   6291456u    // 2097152  (also Xt until k_spat)
#define ST_OFF     TX1_OFF
#define SIGT_OFF   TX2_OFF
#define XT_OFF     XHAT_OFF
#define BST_OFF    8388608u    // bs transposed 262144
#define ET_OFF     8650752u    // (B,16,16) 1024
#define PART_OFF   8651776u    // lhs1 partials 4*8*1024 = 32768
#define RHST_OFF   8684544u    // rhs_t (B,N,T) 32768
#define LHSS_OFF   8717312u    // lhs_s (B,N,T) 32768
#define RHSSN_OFF  8750080u    // rhs_s stored (B,N,T) 32768
#define DIAGS_OFF  8782848u    // (B,N) 2048
#define WSATT_OFF  8784896u    // wS (B,E) 65536
#define CSRW_OFF   8850432u    // 16384
#define WTT_OFF    8866816u    // 12288
#define WRT_OFF    8879104u    // 4096
#define DIS_OFF    8883200u    // 512
#define FEND       8883712u    // floats; ints live after this

// ============ graph prep (parallel, deterministic edge-id order) ============
// per-chunk row histogram: counts[c][r]
__global__ void k_hist(const int* __restrict__ row, int* __restrict__ counts) {
    __shared__ int h[512];
    int c = blockIdx.x, i = threadIdx.x;
    h[i] = 0; h[i + 256] = 0;
    __syncthreads();
    atomicAdd(&h[row[c * 256 + i]], 1);
    __syncthreads();
    counts[c * 512 + i] = h[i];
    counts[c * 512 + i + 256] = h[i + 256];
}

// per-row exclusive prefix over chunks (in-place), deg -> dis, row scan -> row_start
__global__ void k_scan2(int* __restrict__ counts, float* __restrict__ dis,
                        int* __restrict__ row_start) {
    __shared__ int sc[512];
    int r = threadIdx.x;
    int sum = 0;
    for (int c = 0; c < 64; ++c) {
        int v = counts[c * 512 + r];
        counts[c * 512 + r] = sum;    // exclusive chunk base for this row
        sum += v;
    }
    dis[r] = sum > 0 ? 1.0f / sqrtf((float)sum) : 0.0f;
    sc[r] = sum;
    __syncthreads();
    for (int off = 1; off < 512; off <<= 1) {
        int v = sc[r];
        int add = (r >= off) ? sc[r - off] : 0;
        __syncthreads();
        sc[r] = v + add;
        __syncthreads();
    }
    int incl = sc[r];
    row_start[r] = incl - sum;
    if (r == 511) row_start[512] = incl;
}

// rank within chunk (uniform LDS broadcast loop) -> direct CSR slot
__global__ void k_fill2(const int* __restrict__ ei, const int* __restrict__ counts,
                        const int* __restrict__ row_start, const float* __restrict__ dis,
                        int* __restrict__ csr_col, int* __restrict__ csr_row,
                        float* __restrict__ csr_w) {
    __shared__ int rowL[256];
    int c = blockIdx.x, i = threadIdx.x;
    int e = c * 256 + i;
    int r = ei[e];
    int col = ei[NE + e];
    rowL[i] = r;
    __syncthreads();
    int rank = 0;
    for (int j = 0; j < 256; ++j)
        if (j < i && rowL[j] == r) rank++;
    int pos = row_start[r] + counts[c * 512 + r] + rank;
    csr_col[pos] = col;
    csr_row[pos] = r;
    csr_w[pos] = -dis[r] * dis[col];
}

// ============ weight transposes ============
__global__ void k_wprep(const float* __restrict__ Wt, const float* __restrict__ Wr,
                        float* __restrict__ WtT, float* __restrict__ WrT) {
    int idx = blockIdx.x * 256 + threadIdx.x;
    if (idx < 12288) {
        int o = idx & 63, gd = idx >> 6;      // gd = g*3+dt
        int g = gd / 3, dt = gd - g * 3;
        WtT[idx] = Wt[(o * 64 + g) * 3 + dt];
    } else if (idx < 16384) {
        int i2 = idx - 12288;
        int o = i2 & 63, f = i2 >> 6;
        WrT[i2] = Wr[o * 64 + f];
    }
}

__global__ void k_bst(const float* __restrict__ bs, float* __restrict__ bsT) {
    __shared__ float tile[64][65];
    int r0 = blockIdx.y * 64, c0 = blockIdx.x * 64;
    int c = threadIdx.x & 63, rq = threadIdx.x >> 6;
    for (int k = 0; k < 16; ++k) {
        int r = rq * 16 + k;
        tile[r][c] = bs[(r0 + r) * 512 + c0 + c];
    }
    __syncthreads();
    int r2 = threadIdx.x & 63;
    for (int k = 0; k < 16; ++k) {
        int c2 = rq * 16 + k;
        bsT[(size_t)(c0 + c2) * 512 + r0 + r2] = tile[r2][c2];
    }
}

// ============ temporal attention ============
// partial lhs1[b][g][f*16+t] over 64-n chunk
__global__ void k_lhs1_partial(const float* __restrict__ X, const float* __restrict__ U1,
                               float* __restrict__ part) {
    int b = blockIdx.x >> 3, g = blockIdx.x & 7;
    int tid = threadIdx.x;
    float acc[4] = {0.f, 0.f, 0.f, 0.f};
    const float* Xb = X + (size_t)b * NV * 1024;
    int n0 = g * 64;
    for (int nn = 0; nn < 64; ++nn) {
        int n = n0 + nn;
        float u = U1[n];
        const float* xp = Xb + (size_t)n * 1024;
#pragma unroll
        for (int k = 0; k < 4; ++k) acc[k] += xp[tid + 256 * k] * u;
    }
#pragma unroll
    for (int k = 0; k < 4; ++k) part[(size_t)(b * 8 + g) * 1024 + tid + 256 * k] = acc[k];
}

// rhs_t[b][n][t] = sum_f U3[f]*X[b,n,f,t]
__global__ void k_rhs_t(const float* __restrict__ X, const float* __restrict__ U3,
                        float* __restrict__ rhs) {
    int gid = blockIdx.x * 256 + threadIdx.x;
    int t = gid & 15, n = (gid >> 4) & 511, b = gid >> 13;
    const float* xp = X + ((size_t)(b * 512 + n)) * 1024 + t;
    float a = 0.f;
#pragma unroll
    for (int f = 0; f < 64; ++f) a += U3[f] * xp[f * 16];
    rhs[gid] = a;
}

__global__ void k_temporal(const float* __restrict__ part, const float* __restrict__ rhs_g,
                           const float* __restrict__ U2, const float* __restrict__ be,
                           const float* __restrict__ Ve, float* __restrict__ Et) {
    __shared__ float lhs1[1024];
    __shared__ float rhsL[8192];
    __shared__ float M[1024];
    __shared__ float Esig[256];
    __shared__ float Et0[256];
    __shared__ float red[32];
    int b = blockIdx.x, tid = threadIdx.x;
#pragma unroll
    for (int k = 0; k < 4; ++k) {
        int idx = tid + 256 * k;
        float s = 0.f;
        for (int g = 0; g < 8; ++g) s += part[(size_t)(b * 8 + g) * 1024 + idx];
        lhs1[idx] = s;
    }
    for (int k = 0; k < 32; ++k) rhsL[tid + 256 * k] = rhs_g[(size_t)b * 8192 + tid + 256 * k];
    __syncthreads();
    // M[f*16+t] = sum_n U2[f*512+n]*rhsL[n*16+t]
    {
        float acc[4] = {0.f, 0.f, 0.f, 0.f};
        int fA[4], tA[4];
#pragma unroll
        for (int k = 0; k < 4; ++k) { int idx = tid + 256 * k; fA[k] = idx >> 4; tA[k] = idx & 15; }
        for (int n = 0; n < 512; ++n) {
#pragma unroll
            for (int k = 0; k < 4; ++k) acc[k] += U2[fA[k] * 512 + n] * rhsL[n * 16 + tA[k]];
        }
#pragma unroll
        for (int k = 0; k < 4; ++k) M[tid + 256 * k] = acc[k];
    }
    __syncthreads();
    {
        int t1 = tid >> 4, t2 = tid & 15;
        float s = 0.f;
        for (int f = 0; f < 64; ++f) s += lhs1[f * 16 + t1] * M[f * 16 + t2];
        s += be[t1 * 16 + t2];
        Esig[tid] = 1.f / (1.f + expf(-s));
    }
    __syncthreads();
    {
        int t1 = tid >> 4, t2 = tid & 15;
        float s = 0.f;
        for (int k = 0; k < 16; ++k) s += Ve[t1 * 16 + k] * Esig[k * 16 + t2];
        Et0[tid] = s;
    }
    __syncthreads();
    if (tid < 16) {
        float m = -1e30f;
        for (int k = 0; k < 16; ++k) m = fmaxf(m, Et0[k * 16 + tid]);
        float s = 0.f;
        for (int k = 0; k < 16; ++k) s += expf(Et0[k * 16 + tid] - m);
        red[tid] = m; red[16 + tid] = 1.f / s;
    }
    __syncthreads();
    {
        int t2 = tid & 15;
        Et[b * 256 + tid] = expf(Et0[tid] - red[t2]) * red[16 + t2];
    }
}

// ============ Xt = X @ Et ============
__global__ void k_xt(const float* __restrict__ X, const float* __restrict__ Et,
                     float* __restrict__ Xt) {
    __shared__ float EtL[256];
    int tid = threadIdx.x;
    int b = blockIdx.x >> 7;          // 128 blocks per batch
    size_t base = (size_t)blockIdx.x * 256 + tid;   // (b*32768 + nf)
    EtL[tid] = Et[b * 256 + tid];
    __syncthreads();
    const float4* xp = (const float4*)(X + base * 16);
    float4 a0 = xp[0], a1 = xp[1], a2 = xp[2], a3 = xp[3];
    float x[16] = {a0.x, a0.y, a0.z, a0.w, a1.x, a1.y, a1.z, a1.w,
                   a2.x, a2.y, a2.z, a2.w, a3.x, a3.y, a3.z, a3.w};
    float o[16];
#pragma unroll
    for (int t = 0; t < 16; ++t) {
        float s = 0.f;
#pragma unroll
        for (int tp = 0; tp < 16; ++tp) s += x[tp] * EtL[tp * 16 + t];
        o[t] = s;
    }
    float4* op = (float4*)(Xt + base * 16);
    op[0] = make_float4(o[0], o[1], o[2], o[3]);
    op[1] = make_float4(o[4], o[5], o[6], o[7]);
    op[2] = make_float4(o[8], o[9], o[10], o[11]);
    op[3] = make_float4(o[12], o[13], o[14], o[15]);
}

// ============ spatial attention small parts ============
__global__ void k_spat(const float* __restrict__ Xt, const float* __restrict__ Ws1,
                       const float* __restrict__ Ws2, const float* __restrict__ Ws3,
                       float* __restrict__ lhs_s, float* __restrict__ rhs_sn) {
    __shared__ float xl[1024];
    __shared__ float l1[64];
    int bn = blockIdx.x, tid = threadIdx.x;
    const float* xp = Xt + (size_t)bn * 1024;
    for (int k = 0; k < 16; ++k) xl[tid + 64 * k] = xp[tid + 64 * k];
    __syncthreads();
    float s = 0.f;
#pragma unroll
    for (int t = 0; t < 16; ++t) s += xl[tid * 16 + t] * Ws1[t];
    l1[tid] = s;
    __syncthreads();
    if (tid < 16) {
        float a = 0.f;
        for (int f = 0; f < 64; ++f) a += l1[f] * Ws2[f * 16 + tid];
        lhs_s[(size_t)bn * 16 + tid] = a;
    } else if (tid < 32) {
        int t = tid - 16;
        float a = 0.f;
        for (int f = 0; f < 64; ++f) a += Ws3[f] * xl[f * 16 + t];
        rhs_sn[(size_t)bn * 16 + t] = a;
    }
}

// sigT[b][j][k] = sigmoid(lhs_s[b,k,:]·rhs_sn[b,j,:] + bs[k,j])
// grid: B*N*N/256 = 4096 blocks (b = gid>>18)
__global__ void k_sigT(const float* __restrict__ lhs_s, const float* __restrict__ rhs_sn,
                       const float* __restrict__ bsT, float* __restrict__ sigT) {
    int gid = blockIdx.x * 256 + threadIdx.x;
    int k = gid & 511, j = (gid >> 9) & 511, b = gid >> 18;
    const float4* lp = (const float4*)(lhs_s + (size_t)(b * 512 + k) * 16);
    const float4* rp = (const float4*)(rhs_sn + (size_t)(b * 512 + j) * 16);
    float s = 0.f;
#pragma unroll
    for (int q = 0; q < 4; ++q) {
        float4 a = lp[q], c = rp[q];
        s += a.x * c.x + a.y * c.y + a.z * c.z + a.w * c.w;
    }
    s += bsT[(size_t)j * 512 + k];
    sigT[gid] = 1.f / (1.f + expf(-s));
}

// S0T[b][j][i] = sum_k sigT[b][j][k] * Vs[i][k]
__global__ __launch_bounds__(256) void k_gemm_s(const float* __restrict__ sigT,
                                                const float* __restrict__ Vs,
                                                float* __restrict__ S0T) {
    __shared__ float As[64 * 33];
    __shared__ float Bs[64 * 33];
    int bI = blockIdx.x, bJ = blockIdx.y, b = blockIdx.z;
    int tid = threadIdx.x, tx = tid & 15, ty = tid >> 4;
    float acc[4][4] = {};
    const float* Ab = sigT + ((size_t)b * 512 + bJ * 64) * 512;
    const float* Bb = Vs + (size_t)bI * 64 * 512;
    for (int k0 = 0; k0 < 512; k0 += 32) {
#pragma unroll
        for (int p = 0; p < 2; ++p) {
            int idx = tid + 256 * p;
            int row = idx >> 3, kk = (idx & 7) * 4;
            float4 a = *(const float4*)(Ab + (size_t)row * 512 + k0 + kk);
            As[row * 33 + kk] = a.x; As[row * 33 + kk + 1] = a.y;
            As[row * 33 + kk + 2] = a.z; As[row * 33 + kk + 3] = a.w;
            float4 v = *(const float4*)(Bb + (size_t)row * 512 + k0 + kk);
            Bs[row * 33 + kk] = v.x; Bs[row * 33 + kk + 1] = v.y;
            Bs[row * 33 + kk + 2] = v.z; Bs[row * 33 + kk + 3] = v.w;
        }
        __syncthreads();
#pragma unroll
        for (int kk = 0; kk < 32; ++kk) {
            float a[4], bb[4];
#pragma unroll
            for (int q = 0; q < 4; ++q) a[q] = As[(ty * 4 + q) * 33 + kk];
#pragma unroll
            for (int q = 0; q < 4; ++q) bb[q] = Bs[(tx * 4 + q) * 33 + kk];
#pragma unroll
            for (int y = 0; y < 4; ++y)
#pragma unroll
                for (int x = 0; x < 4; ++x) acc[y][x] += a[y] * bb[x];
        }
        __syncthreads();
    }
    float* Cb = S0T + ((size_t)b * 512 + bJ * 64) * 512 + bI * 64;
#pragma unroll
    for (int y = 0; y < 4; ++y) {
        int j = ty * 4 + y;
        *(float4*)(Cb + (size_t)j * 512 + tx * 4) =
            make_float4(acc[y][0], acc[y][1], acc[y][2], acc[y][3]);
    }
}

// softmax over i (contiguous) in-place; extract diagonal
__global__ void k_softmax_s(float* __restrict__ ST, float* __restrict__ diagS) {
    __shared__ float red[4];
    int bj = blockIdx.x;
    int b = bj >> 9, j = bj & 511;
    float* row = ST + (size_t)bj * 512;
    int tid = threadIdx.x;
    float v0 = row[tid], v1 = row[tid + 256];
    float m = fmaxf(v0, v1);
    for (int off = 32; off; off >>= 1) m = fmaxf(m, __shfl_xor(m, off));
    if ((tid & 63) == 0) red[tid >> 6] = m;
    __syncthreads();
    m = fmaxf(fmaxf(red[0], red[1]), fmaxf(red[2], red[3]));
    __syncthreads();
    float e0 = expf(v0 - m), e1 = expf(v1 - m);
    float s = e0 + e1;
    for (int off = 32; off; off >>= 1) s += __shfl_xor(s, off);
    if ((tid & 63) == 0) red[tid >> 6] = s;
    __syncthreads();
    s = red[0] + red[1] + red[2] + red[3];
    float inv = 1.f / s;
    float r0 = e0 * inv, r1 = e1 * inv;
    row[tid] = r0;
    row[tid + 256] = r1;
    if (j < 256) { if (tid == j) diagS[b * 512 + j] = r0; }
    else { if (tid == j - 256) diagS[b * 512 + j] = r1; }
}

// wS[b][pos] = csr_w[pos] * S[b, row, col] = csr_w * ST[b][col][row]
__global__ void k_wS(const int* __restrict__ csr_col, const int* __restrict__ csr_row,
                     const float* __restrict__ csr_w, const float* __restrict__ ST,
                     float* __restrict__ wS) {
    int gid = blockIdx.x * 256 + threadIdx.x;
    int pos = gid & (NE - 1), b = gid >> 14;
    int c = csr_col[pos], r = csr_row[pos];
    wS[gid] = csr_w[pos] * ST[((size_t)(b * 512 + c)) * 512 + r];
}

// Tx0[bt][n][f] = diagS[b,n]*X[b,n,f,t]
__global__ void k_tx0(const float* __restrict__ X, const float* __restrict__ diagS,
                      float* __restrict__ Tx0) {
    __shared__ float xl[1088];   // [f][t] padded 17
    int bn = blockIdx.x;
    int b = bn >> 9, n = bn & 511;
    int tid = threadIdx.x;
    const float* xp = X + (size_t)bn * 1024;
#pragma unroll
    for (int k = 0; k < 4; ++k) {
        int idx = tid + 256 * k;
        xl[(idx >> 4) * 17 + (idx & 15)] = xp[idx];
    }
    float s = diagS[bn];
    __syncthreads();
    int f = tid & 63, tg = tid >> 6;
#pragma unroll
    for (int tt = 0; tt < 4; ++tt) {
        int t = tg * 4 + tt;
        Tx0[(((size_t)b * 16 + t) * 512 + n) * 64 + f] = xl[f * 17 + t] * s;
    }
}

__global__ void k_prop1(const float* __restrict__ Tx0, const float* __restrict__ wS,
                        const int* __restrict__ csr_col, const int* __restrict__ row_start,
                        float* __restrict__ Tx1) {
    int blk = blockIdx.x;
    int i = blk & 511, bt = blk >> 9, b = blk >> 13;
    int f = threadIdx.x;
    int s = row_start[i], e2 = row_start[i + 1];
    const float* base = Tx0 + (size_t)bt * 512 * 64;
    const float* wb = wS + (size_t)b * NE;
    float acc = 0.f;
    for (int p = s; p < e2; ++p)
        acc += wb[p] * base[(size_t)csr_col[p] * 64 + f];
    Tx1[((size_t)bt * 512 + i) * 64 + f] = acc;
}

__global__ void k_prop2(const float* __restrict__ Tx1, const float* __restrict__ Tx0,
                        const float* __restrict__ csr_w, const int* __restrict__ csr_col,
                        const int* __restrict__ row_start, float* __restrict__ Tx2) {
    int blk = blockIdx.x;
    int i = blk & 511, bt = blk >> 9;
    int f = threadIdx.x;
    int s = row_start[i], e2 = row_start[i + 1];
    const float* base = Tx1 + (size_t)bt * 512 * 64;
    float acc = 0.f;
    for (int p = s; p < e2; ++p)
        acc += csr_w[p] * base[(size_t)csr_col[p] * 64 + f];
    size_t oi = ((size_t)bt * 512 + i) * 64 + f;
    Tx2[oi] = 2.f * acc - Tx0[oi];
}

// X_hat = relu(Tx0@W0 + Tx1@W1 + Tx2@W2 + b_cheb)
__global__ __launch_bounds__(256) void k_cheb(const float* __restrict__ Tx0,
                                              const float* __restrict__ Tx1,
                                              const float* __restrict__ Tx2,
                                              const float* __restrict__ Wc,
                                              const float* __restrict__ bc,
                                              float* __restrict__ Xh) {
    __shared__ float Wl[3 * 4096];
    __shared__ float t0s[1024], t1s[1024], t2s[1024];
    __shared__ float bcl[64];
    int tid = threadIdx.x;
#pragma unroll
    for (int k = 0; k < 48; ++k) Wl[tid + 256 * k] = Wc[tid + 256 * k];
    if (tid < 64) bcl[tid] = bc[tid];
    int g = tid & 63, r0 = tid >> 6;
    size_t rbase = (size_t)blockIdx.x * 64;
    float acc[16];
#pragma unroll
    for (int k = 0; k < 16; ++k) acc[k] = 0.f;
    for (int f0 = 0; f0 < 64; f0 += 16) {
        __syncthreads();
#pragma unroll
        for (int p = 0; p < 4; ++p) {
            int idx = tid + 256 * p;
            int row = idx >> 4, ff = idx & 15;
            size_t gi = (rbase + row) * 64 + f0 + ff;
            t0s[idx] = Tx0[gi];
            t1s[idx] = Tx1[gi];
            t2s[idx] = Tx2[gi];
        }
        __syncthreads();
        for (int ff = 0; ff < 16; ++ff) {
            int f = f0 + ff;
            float w0 = Wl[f * 64 + g], w1 = Wl[4096 + f * 64 + g], w2 = Wl[8192 + f * 64 + g];
#pragma unroll
            for (int k = 0; k < 16; ++k) {
                int row = r0 + 4 * k;
                acc[k] += t0s[row * 16 + ff] * w0 + t1s[row * 16 + ff] * w1 + t2s[row * 16 + ff] * w2;
            }
        }
    }
#pragma unroll
    for (int k = 0; k < 16; ++k) {
        size_t r = rbase + r0 + 4 * k;
        Xh[r * 64 + g] = fmaxf(acc[k] + bcl[g], 0.f);
    }
}

// fused time-conv + residual conv + relu + LayerNorm + output transpose
__global__ __launch_bounds__(256) void k_out(const float* __restrict__ X,
                                             const float* __restrict__ Xh,
                                             const float* __restrict__ WtT,
                                             const float* __restrict__ WrT,
                                             const float* __restrict__ bt,
                                             const float* __restrict__ br,
                                             const float* __restrict__ gamma,
                                             const float* __restrict__ beta,
                                             float* __restrict__ out) {
    __shared__ float Wl[12288];   // [(g*3+dt)*64+o]
    __shared__ float xh[1024];    // [t][g]
    __shared__ float xl[1088];    // [f][t] padded 17
    __shared__ float z[1024];     // [t][o]
    int bn = blockIdx.x;
    int b = bn >> 9, n = bn & 511;
    int tid = threadIdx.x;
#pragma unroll
    for (int k = 0; k < 48; ++k) Wl[tid + 256 * k] = WtT[tid + 256 * k];
#pragma unroll
    for (int k = 0; k < 4; ++k) {
        int idx = tid + 256 * k;
        xl[(idx >> 4) * 17 + (idx & 15)] = X[(size_t)bn * 1024 + idx];
    }
#pragma unroll
    for (int k = 0; k < 4; ++k) {
        int idx = tid + 256 * k;
        int t = idx >> 6, g = idx & 63;
        xh[idx] = Xh[(((size_t)b * 16 + t) * 512 + n) * 64 + g];
    }
    __syncthreads();
    int o = tid & 63, tg = tid >> 6;
    float bto = bt[o], bro = br[o], go = gamma[o], bo = beta[o];
    for (int tt = 0; tt < 4; ++tt) {
        int t = tg * 4 + tt;
        float ct = bto;
#pragma unroll
        for (int dt = 0; dt < 3; ++dt) {
            int ts = t + dt - 1;
            if (ts < 0 || ts > 15) continue;
            for (int g = 0; g < 64; ++g)
                ct += xh[ts * 64 + g] * Wl[(g * 3 + dt) * 64 + o];
        }
        float cr = bro;
        for (int f = 0; f < 64; ++f) cr += xl[f * 17 + t] * WrT[f * 64 + o];
        float zv = fmaxf(ct + cr, 0.f);
        float s = zv, sq = zv * zv;
        for (int off = 32; off; off >>= 1) {
            s += __shfl_xor(s, off);
            sq += __shfl_xor(sq, off);
        }
        float mu = s * (1.f / 64.f);
        float var = sq * (1.f / 64.f) - mu * mu;
        float zn = (zv - mu) * rsqrtf(var + 1e-5f) * go + bo;
        z[t * 64 + o] = zn;
    }
    __syncthreads();
#pragma unroll
    for (int k = 0; k < 4; ++k) {
        int i = tid + 256 * k;
        out[(size_t)bn * 1024 + i] = z[(i & 15) * 64 + (i >> 4)];
    }
}

extern "C" void kernel_launch(void* const* d_in, const int* in_sizes, int n_in,
                              void* d_out, int out_size, void* d_ws, size_t ws_size,
                              hipStream_t stream) {
    const float* X     = (const float*)d_in[0];
    const int*   ei    = (const int*)d_in[1];
    const float* U1    = (const float*)d_in[2];
    const float* U2    = (const float*)d_in[3];
    const float* U3    = (const float*)d_in[4];
    const float* be    = (const float*)d_in[5];
    const float* Ve    = (const float*)d_in[6];
    const float* Ws1   = (const float*)d_in[7];
    const float* Ws2   = (const float*)d_in[8];
    const float* Ws3   = (const float*)d_in[9];
    const float* bs    = (const float*)d_in[10];
    const float* Vs    = (const float*)d_in[11];
    const float* Wc    = (const float*)d_in[12];
    const float* bc    = (const float*)d_in[13];
    const float* Wt    = (const float*)d_in[14];
    const float* bt    = (const float*)d_in[15];
    const float* Wr    = (const float*)d_in[16];
    const float* br    = (const float*)d_in[17];
    const float* gamma = (const float*)d_in[18];
    const float* beta  = (const float*)d_in[19];

    float* ws = (float*)d_ws;
    float* Tx0    = ws + TX0_OFF;
    float* Tx1    = ws + TX1_OFF;
    float* Tx2    = ws + TX2_OFF;
    float* Xh     = ws + XHAT_OFF;
    float* Xt     = ws + XT_OFF;     // shares XHAT (dead before k_cheb)
    float* ST     = ws + ST_OFF;     // shares TX1 (dead before k_prop1)
    float* sigT   = ws + SIGT_OFF;   // shares TX2 (dead before k_prop2)
    float* bsT    = ws + BST_OFF;
    float* Et     = ws + ET_OFF;
    float* part   = ws + PART_OFF;
    float* rhs_t  = ws + RHST_OFF;
    float* lhs_s  = ws + LHSS_OFF;
    float* rhs_sn = ws + RHSSN_OFF;
    float* diagS  = ws + DIAGS_OFF;
    float* wS     = ws + WSATT_OFF;
    float* csr_w  = ws + CSRW_OFF;
    float* WtT    = ws + WTT_OFF;
    float* WrT    = ws + WRT_OFF;
    float* dis    = ws + DIS_OFF;

    int* ib        = (int*)(ws + FEND);
    int* row_start = ib;                  // 513 (pad to 516)
    int* csr_col   = ib + 516;            // NE
    int* csr_row   = csr_col + NE;        // NE
    int* counts    = csr_row + NE;        // 64*512

    // graph prep (parallel, deterministic)
    k_hist<<<64, 256, 0, stream>>>(ei, counts);
    k_scan2<<<1, 512, 0, stream>>>(counts, dis, row_start);
    k_fill2<<<64, 256, 0, stream>>>(ei, counts, row_start, dis, csr_col, csr_row, csr_w);

    // weight transposes (independent)
    k_wprep<<<64, 256, 0, stream>>>(Wt, Wr, WtT, WrT);
    k_bst<<<dim3(8, 8), 256, 0, stream>>>(bs, bsT);

    // temporal attention
    k_lhs1_partial<<<32, 256, 0, stream>>>(X, U1, part);
    k_rhs_t<<<128, 256, 0, stream>>>(X, U3, rhs_t);
    k_temporal<<<4, 256, 0, stream>>>(part, rhs_t, U2, be, Ve, Et);
    k_xt<<<512, 256, 0, stream>>>(X, Et, Xt);

    // spatial attention
    k_spat<<<2048, 64, 0, stream>>>(Xt, Ws1, Ws2, Ws3, lhs_s, rhs_sn);
    k_sigT<<<4096, 256, 0, stream>>>(lhs_s, rhs_sn, bsT, sigT);   // B*N*N/256
    k_gemm_s<<<dim3(8, 8, 4), 256, 0, stream>>>(sigT, Vs, ST);
    k_softmax_s<<<2048, 256, 0, stream>>>(ST, diagS);
    k_wS<<<256, 256, 0, stream>>>(csr_col, csr_row, csr_w, ST, wS);

    // chebyshev conv
    k_tx0<<<2048, 256, 0, stream>>>(X, diagS, Tx0);
    k_prop1<<<32768, 64, 0, stream>>>(Tx0, wS, csr_col, row_start, Tx1);
    k_prop2<<<32768, 64, 0, stream>>>(Tx1, Tx0, csr_w, csr_col, row_start, Tx2);
    k_cheb<<<512, 256, 0, stream>>>(Tx0, Tx1, Tx2, Wc, bc, Xh);

    // time conv + residual + LN + transpose
    k_out<<<2048, 256, 0, stream>>>(X, Xh, WtT, WrT, bt, br, gamma, beta, (float*)d_out);
}

// Round 4
// 271.013 us; speedup vs baseline: 1.7904x; 1.1497x over previous
//
#include <hip/hip_runtime.h>
#include <math.h>

#define NB 4
#define NV 512
#define NF 64
#define NT 16
#define NE 16384

// ---------------- workspace layout (float offsets) ----------------
// Overlapped lifetimes: Xt shares XHAT, ST shares TX1, sigT shares TX2.
#define TX0_OFF    0u          // (B*T,N,F)  2097152
#define TX1_OFF    2097152u    // 2097152  (also ST until k_wS)
#define TX2_OFF    4194304u    // 2097152  (also sigT until k_gemm_s)
#define XHAT_OFF   6291456u    // 2097152  (also Xt until k_spat)
#define ST_OFF     TX1_OFF
#define SIGT_OFF   TX2_OFF
#define XT_OFF     XHAT_OFF
#define BST_OFF    8388608u    // bs transposed 262144
#define ET_OFF     8650752u    // (B,16,16) 1024
#define PART_OFF   8651776u    // lhs1 partials 4*8*1024 = 32768
#define RHST_OFF   8684544u    // rhs_t (B,N,T) 32768
#define LHSS_OFF   8717312u    // lhs_s (B,N,T) 32768
#define RHSSN_OFF  8750080u    // rhs_s stored (B,N,T) 32768
#define DIAGS_OFF  8782848u    // (B,N) 2048
#define WSATT_OFF  8784896u    // wS (B,E) 65536
#define CSRW_OFF   8850432u    // 16384
#define WTT_OFF    8866816u    // 12288
#define WRT_OFF    8879104u    // 4096
#define DIS_OFF    8883200u    // 512
#define FEND       8883712u    // floats; ints live after this

// ============ graph prep (parallel, deterministic edge-id order) ============
__global__ void k_hist(const int* __restrict__ row, int* __restrict__ counts) {
    __shared__ int h[512];
    int c = blockIdx.x, i = threadIdx.x;
    h[i] = 0; h[i + 256] = 0;
    __syncthreads();
    atomicAdd(&h[row[c * 256 + i]], 1);
    __syncthreads();
    counts[c * 512 + i] = h[i];
    counts[c * 512 + i + 256] = h[i + 256];
}

__global__ void k_scan2(int* __restrict__ counts, float* __restrict__ dis,
                        int* __restrict__ row_start) {
    __shared__ int sc[512];
    int r = threadIdx.x;
    int sum = 0;
    for (int c = 0; c < 64; ++c) {
        int v = counts[c * 512 + r];
        counts[c * 512 + r] = sum;    // exclusive chunk base for this row
        sum += v;
    }
    dis[r] = sum > 0 ? 1.0f / sqrtf((float)sum) : 0.0f;
    sc[r] = sum;
    __syncthreads();
    for (int off = 1; off < 512; off <<= 1) {
        int v = sc[r];
        int add = (r >= off) ? sc[r - off] : 0;
        __syncthreads();
        sc[r] = v + add;
        __syncthreads();
    }
    int incl = sc[r];
    row_start[r] = incl - sum;
    if (r == 511) row_start[512] = incl;
}

__global__ void k_fill2(const int* __restrict__ ei, const int* __restrict__ counts,
                        const int* __restrict__ row_start, const float* __restrict__ dis,
                        int* __restrict__ csr_col, int* __restrict__ csr_row,
                        float* __restrict__ csr_w) {
    __shared__ int rowL[256];
    int c = blockIdx.x, i = threadIdx.x;
    int e = c * 256 + i;
    int r = ei[e];
    int col = ei[NE + e];
    rowL[i] = r;
    __syncthreads();
    int rank = 0;
    for (int j = 0; j < 256; ++j)
        if (j < i && rowL[j] == r) rank++;
    int pos = row_start[r] + counts[c * 512 + r] + rank;
    csr_col[pos] = col;
    csr_row[pos] = r;
    csr_w[pos] = -dis[r] * dis[col];
}

// ============ weight transposes ============
__global__ void k_wprep(const float* __restrict__ Wt, const float* __restrict__ Wr,
                        float* __restrict__ WtT, float* __restrict__ WrT) {
    int idx = blockIdx.x * 256 + threadIdx.x;
    if (idx < 12288) {
        int o = idx & 63, gd = idx >> 6;      // gd = g*3+dt
        int g = gd / 3, dt = gd - g * 3;
        WtT[idx] = Wt[(o * 64 + g) * 3 + dt];
    } else if (idx < 16384) {
        int i2 = idx - 12288;
        int o = i2 & 63, f = i2 >> 6;
        WrT[i2] = Wr[o * 64 + f];
    }
}

__global__ void k_bst(const float* __restrict__ bs, float* __restrict__ bsT) {
    __shared__ float tile[64][65];
    int r0 = blockIdx.y * 64, c0 = blockIdx.x * 64;
    int c = threadIdx.x & 63, rq = threadIdx.x >> 6;
    for (int k = 0; k < 16; ++k) {
        int r = rq * 16 + k;
        tile[r][c] = bs[(r0 + r) * 512 + c0 + c];
    }
    __syncthreads();
    int r2 = threadIdx.x & 63;
    for (int k = 0; k < 16; ++k) {
        int c2 = rq * 16 + k;
        bsT[(size_t)(c0 + c2) * 512 + r0 + r2] = tile[r2][c2];
    }
}

// ============ temporal attention ============
__global__ void k_lhs1_partial(const float* __restrict__ X, const float* __restrict__ U1,
                               float* __restrict__ part) {
    int b = blockIdx.x >> 3, g = blockIdx.x & 7;
    int tid = threadIdx.x;
    float acc[4] = {0.f, 0.f, 0.f, 0.f};
    const float* Xb = X + (size_t)b * NV * 1024;
    int n0 = g * 64;
    for (int nn = 0; nn < 64; ++nn) {
        int n = n0 + nn;
        float u = U1[n];
        const float* xp = Xb + (size_t)n * 1024;
#pragma unroll
        for (int k = 0; k < 4; ++k) acc[k] += xp[tid + 256 * k] * u;
    }
#pragma unroll
    for (int k = 0; k < 4; ++k) part[(size_t)(b * 8 + g) * 1024 + tid + 256 * k] = acc[k];
}

__global__ void k_rhs_t(const float* __restrict__ X, const float* __restrict__ U3,
                        float* __restrict__ rhs) {
    int gid = blockIdx.x * 256 + threadIdx.x;
    int t = gid & 15, n = (gid >> 4) & 511, b = gid >> 13;
    const float* xp = X + ((size_t)(b * 512 + n)) * 1024 + t;
    float a = 0.f;
#pragma unroll
    for (int f = 0; f < 64; ++f) a += U3[f] * xp[f * 16];
    rhs[gid] = a;
}

__global__ void k_temporal(const float* __restrict__ part, const float* __restrict__ rhs_g,
                           const float* __restrict__ U2, const float* __restrict__ be,
                           const float* __restrict__ Ve, float* __restrict__ Et) {
    __shared__ float lhs1[1024];
    __shared__ float rhsL[8192];
    __shared__ float M[1024];
    __shared__ float Esig[256];
    __shared__ float Et0[256];
    __shared__ float red[32];
    int b = blockIdx.x, tid = threadIdx.x;
#pragma unroll
    for (int k = 0; k < 4; ++k) {
        int idx = tid + 256 * k;
        float s = 0.f;
        for (int g = 0; g < 8; ++g) s += part[(size_t)(b * 8 + g) * 1024 + idx];
        lhs1[idx] = s;
    }
    for (int k = 0; k < 32; ++k) rhsL[tid + 256 * k] = rhs_g[(size_t)b * 8192 + tid + 256 * k];
    __syncthreads();
    {
        float acc[4] = {0.f, 0.f, 0.f, 0.f};
        int fA[4], tA[4];
#pragma unroll
        for (int k = 0; k < 4; ++k) { int idx = tid + 256 * k; fA[k] = idx >> 4; tA[k] = idx & 15; }
        for (int n = 0; n < 512; ++n) {
#pragma unroll
            for (int k = 0; k < 4; ++k) acc[k] += U2[fA[k] * 512 + n] * rhsL[n * 16 + tA[k]];
        }
#pragma unroll
        for (int k = 0; k < 4; ++k) M[tid + 256 * k] = acc[k];
    }
    __syncthreads();
    {
        int t1 = tid >> 4, t2 = tid & 15;
        float s = 0.f;
        for (int f = 0; f < 64; ++f) s += lhs1[f * 16 + t1] * M[f * 16 + t2];
        s += be[t1 * 16 + t2];
        Esig[tid] = 1.f / (1.f + expf(-s));
    }
    __syncthreads();
    {
        int t1 = tid >> 4, t2 = tid & 15;
        float s = 0.f;
        for (int k = 0; k < 16; ++k) s += Ve[t1 * 16 + k] * Esig[k * 16 + t2];
        Et0[tid] = s;
    }
    __syncthreads();
    if (tid < 16) {
        float m = -1e30f;
        for (int k = 0; k < 16; ++k) m = fmaxf(m, Et0[k * 16 + tid]);
        float s = 0.f;
        for (int k = 0; k < 16; ++k) s += expf(Et0[k * 16 + tid] - m);
        red[tid] = m; red[16 + tid] = 1.f / s;
    }
    __syncthreads();
    {
        int t2 = tid & 15;
        Et[b * 256 + tid] = expf(Et0[tid] - red[t2]) * red[16 + t2];
    }
}

// ============ Xt = X @ Et ============
__global__ void k_xt(const float* __restrict__ X, const float* __restrict__ Et,
                     float* __restrict__ Xt) {
    __shared__ float EtL[256];
    int tid = threadIdx.x;
    int b = blockIdx.x >> 7;
    size_t base = (size_t)blockIdx.x * 256 + tid;
    EtL[tid] = Et[b * 256 + tid];
    __syncthreads();
    const float4* xp = (const float4*)(X + base * 16);
    float4 a0 = xp[0], a1 = xp[1], a2 = xp[2], a3 = xp[3];
    float x[16] = {a0.x, a0.y, a0.z, a0.w, a1.x, a1.y, a1.z, a1.w,
                   a2.x, a2.y, a2.z, a2.w, a3.x, a3.y, a3.z, a3.w};
    float o[16];
#pragma unroll
    for (int t = 0; t < 16; ++t) {
        float s = 0.f;
#pragma unroll
        for (int tp = 0; tp < 16; ++tp) s += x[tp] * EtL[tp * 16 + t];
        o[t] = s;
    }
    float4* op = (float4*)(Xt + base * 16);
    op[0] = make_float4(o[0], o[1], o[2], o[3]);
    op[1] = make_float4(o[4], o[5], o[6], o[7]);
    op[2] = make_float4(o[8], o[9], o[10], o[11]);
    op[3] = make_float4(o[12], o[13], o[14], o[15]);
}

// ============ spatial attention small parts ============
__global__ void k_spat(const float* __restrict__ Xt, const float* __restrict__ Ws1,
                       const float* __restrict__ Ws2, const float* __restrict__ Ws3,
                       float* __restrict__ lhs_s, float* __restrict__ rhs_sn) {
    __shared__ float xl[1024];
    __shared__ float l1[64];
    int bn = blockIdx.x, tid = threadIdx.x;
    const float* xp = Xt + (size_t)bn * 1024;
    for (int k = 0; k < 16; ++k) xl[tid + 64 * k] = xp[tid + 64 * k];
    __syncthreads();
    float s = 0.f;
#pragma unroll
    for (int t = 0; t < 16; ++t) s += xl[tid * 16 + t] * Ws1[t];
    l1[tid] = s;
    __syncthreads();
    if (tid < 16) {
        float a = 0.f;
        for (int f = 0; f < 64; ++f) a += l1[f] * Ws2[f * 16 + tid];
        lhs_s[(size_t)bn * 16 + tid] = a;
    } else if (tid < 32) {
        int t = tid - 16;
        float a = 0.f;
        for (int f = 0; f < 64; ++f) a += Ws3[f] * xl[f * 16 + t];
        rhs_sn[(size_t)bn * 16 + t] = a;
    }
}

// grid: B*N*N/256 = 4096 blocks (b = gid>>18)
__global__ void k_sigT(const float* __restrict__ lhs_s, const float* __restrict__ rhs_sn,
                       const float* __restrict__ bsT, float* __restrict__ sigT) {
    int gid = blockIdx.x * 256 + threadIdx.x;
    int k = gid & 511, j = (gid >> 9) & 511, b = gid >> 18;
    const float4* lp = (const float4*)(lhs_s + (size_t)(b * 512 + k) * 16);
    const float4* rp = (const float4*)(rhs_sn + (size_t)(b * 512 + j) * 16);
    float s = 0.f;
#pragma unroll
    for (int q = 0; q < 4; ++q) {
        float4 a = lp[q], c = rp[q];
        s += a.x * c.x + a.y * c.y + a.z * c.z + a.w * c.w;
    }
    s += bsT[(size_t)j * 512 + k];
    sigT[gid] = 1.f / (1.f + expf(-s));
}

// S0T[b][j][i] = sum_k sigT[b][j][k] * Vs[i][k]
__global__ __launch_bounds__(256) void k_gemm_s(const float* __restrict__ sigT,
                                                const float* __restrict__ Vs,
                                                float* __restrict__ S0T) {
    __shared__ float As[64 * 33];
    __shared__ float Bs[64 * 33];
    int bI = blockIdx.x, bJ = blockIdx.y, b = blockIdx.z;
    int tid = threadIdx.x, tx = tid & 15, ty = tid >> 4;
    float acc[4][4] = {};
    const float* Ab = sigT + ((size_t)b * 512 + bJ * 64) * 512;
    const float* Bb = Vs + (size_t)bI * 64 * 512;
    for (int k0 = 0; k0 < 512; k0 += 32) {
#pragma unroll
        for (int p = 0; p < 2; ++p) {
            int idx = tid + 256 * p;
            int row = idx >> 3, kk = (idx & 7) * 4;
            float4 a = *(const float4*)(Ab + (size_t)row * 512 + k0 + kk);
            As[row * 33 + kk] = a.x; As[row * 33 + kk + 1] = a.y;
            As[row * 33 + kk + 2] = a.z; As[row * 33 + kk + 3] = a.w;
            float4 v = *(const float4*)(Bb + (size_t)row * 512 + k0 + kk);
            Bs[row * 33 + kk] = v.x; Bs[row * 33 + kk + 1] = v.y;
            Bs[row * 33 + kk + 2] = v.z; Bs[row * 33 + kk + 3] = v.w;
        }
        __syncthreads();
#pragma unroll
        for (int kk = 0; kk < 32; ++kk) {
            float a[4], bb[4];
#pragma unroll
            for (int q = 0; q < 4; ++q) a[q] = As[(ty * 4 + q) * 33 + kk];
#pragma unroll
            for (int q = 0; q < 4; ++q) bb[q] = Bs[(tx * 4 + q) * 33 + kk];
#pragma unroll
            for (int y = 0; y < 4; ++y)
#pragma unroll
                for (int x = 0; x < 4; ++x) acc[y][x] += a[y] * bb[x];
        }
        __syncthreads();
    }
    float* Cb = S0T + ((size_t)b * 512 + bJ * 64) * 512 + bI * 64;
#pragma unroll
    for (int y = 0; y < 4; ++y) {
        int j = ty * 4 + y;
        *(float4*)(Cb + (size_t)j * 512 + tx * 4) =
            make_float4(acc[y][0], acc[y][1], acc[y][2], acc[y][3]);
    }
}

// softmax over i (contiguous) in-place; extract diagonal
__global__ void k_softmax_s(float* __restrict__ ST, float* __restrict__ diagS) {
    __shared__ float red[4];
    int bj = blockIdx.x;
    int b = bj >> 9, j = bj & 511;
    float* row = ST + (size_t)bj * 512;
    int tid = threadIdx.x;
    float v0 = row[tid], v1 = row[tid + 256];
    float m = fmaxf(v0, v1);
    for (int off = 32; off; off >>= 1) m = fmaxf(m, __shfl_xor(m, off));
    if ((tid & 63) == 0) red[tid >> 6] = m;
    __syncthreads();
    m = fmaxf(fmaxf(red[0], red[1]), fmaxf(red[2], red[3]));
    __syncthreads();
    float e0 = expf(v0 - m), e1 = expf(v1 - m);
    float s = e0 + e1;
    for (int off = 32; off; off >>= 1) s += __shfl_xor(s, off);
    if ((tid & 63) == 0) red[tid >> 6] = s;
    __syncthreads();
    s = red[0] + red[1] + red[2] + red[3];
    float inv = 1.f / s;
    float r0 = e0 * inv, r1 = e1 * inv;
    row[tid] = r0;
    row[tid + 256] = r1;
    if (j < 256) { if (tid == j) diagS[b * 512 + j] = r0; }
    else { if (tid == j - 256) diagS[b * 512 + j] = r1; }
}

// wS[b][pos] = csr_w[pos] * ST[b][col][row]
__global__ void k_wS(const int* __restrict__ csr_col, const int* __restrict__ csr_row,
                     const float* __restrict__ csr_w, const float* __restrict__ ST,
                     float* __restrict__ wS) {
    int gid = blockIdx.x * 256 + threadIdx.x;
    int pos = gid & (NE - 1), b = gid >> 14;
    int c = csr_col[pos], r = csr_row[pos];
    wS[gid] = csr_w[pos] * ST[((size_t)(b * 512 + c)) * 512 + r];
}

// Tx0[bt][n][f] = diagS[b,n]*X[b,n,f,t]
__global__ void k_tx0(const float* __restrict__ X, const float* __restrict__ diagS,
                      float* __restrict__ Tx0) {
    __shared__ float xl[1088];   // [f][t] padded 17
    int bn = blockIdx.x;
    int b = bn >> 9, n = bn & 511;
    int tid = threadIdx.x;
    const float* xp = X + (size_t)bn * 1024;
#pragma unroll
    for (int k = 0; k < 4; ++k) {
        int idx = tid + 256 * k;
        xl[(idx >> 4) * 17 + (idx & 15)] = xp[idx];
    }
    float s = diagS[bn];
    __syncthreads();
    int f = tid & 63, tg = tid >> 6;
#pragma unroll
    for (int tt = 0; tt < 4; ++tt) {
        int t = tg * 4 + tt;
        Tx0[(((size_t)b * 16 + t) * 512 + n) * 64 + f] = xl[f * 17 + t] * s;
    }
}

__global__ void k_prop1(const float* __restrict__ Tx0, const float* __restrict__ wS,
                        const int* __restrict__ csr_col, const int* __restrict__ row_start,
                        float* __restrict__ Tx1) {
    int blk = blockIdx.x;
    int i = blk & 511, bt = blk >> 9, b = blk >> 13;
    int f = threadIdx.x;
    int s = row_start[i], e2 = row_start[i + 1];
    const float* base = Tx0 + (size_t)bt * 512 * 64;
    const float* wb = wS + (size_t)b * NE;
    float acc = 0.f;
    for (int p = s; p < e2; ++p)
        acc += wb[p] * base[(size_t)csr_col[p] * 64 + f];
    Tx1[((size_t)bt * 512 + i) * 64 + f] = acc;
}

__global__ void k_prop2(const float* __restrict__ Tx1, const float* __restrict__ Tx0,
                        const float* __restrict__ csr_w, const int* __restrict__ csr_col,
                        const int* __restrict__ row_start, float* __restrict__ Tx2) {
    int blk = blockIdx.x;
    int i = blk & 511, bt = blk >> 9;
    int f = threadIdx.x;
    int s = row_start[i], e2 = row_start[i + 1];
    const float* base = Tx1 + (size_t)bt * 512 * 64;
    float acc = 0.f;
    for (int p = s; p < e2; ++p)
        acc += csr_w[p] * base[(size_t)csr_col[p] * 64 + f];
    size_t oi = ((size_t)bt * 512 + i) * 64 + f;
    Tx2[oi] = 2.f * acc - Tx0[oi];
}

// X_hat = relu(Tx0@W0 + Tx1@W1 + Tx2@W2 + b_cheb)
// register-tiled: thread = (4 rows x 4 g), weights via float4 global (L1-hot)
__global__ __launch_bounds__(256) void k_cheb(const float* __restrict__ Tx0,
                                              const float* __restrict__ Tx1,
                                              const float* __restrict__ Tx2,
                                              const float* __restrict__ Wc,
                                              const float* __restrict__ bc,
                                              float* __restrict__ Xh) {
    __shared__ float t0s[64 * 17], t1s[64 * 17], t2s[64 * 17];
    int tid = threadIdx.x;
    int g4 = (tid & 15) * 4, r0 = (tid >> 4) * 4;
    size_t rbase = (size_t)blockIdx.x * 64;
    float acc[4][4] = {};
    for (int f0 = 0; f0 < 64; f0 += 16) {
        __syncthreads();
#pragma unroll
        for (int p = 0; p < 4; ++p) {
            int idx = tid + 256 * p;
            int row = idx >> 4, ff = idx & 15;
            size_t gi = (rbase + row) * 64 + f0 + ff;
            t0s[row * 17 + ff] = Tx0[gi];
            t1s[row * 17 + ff] = Tx1[gi];
            t2s[row * 17 + ff] = Tx2[gi];
        }
        __syncthreads();
        for (int ff = 0; ff < 16; ++ff) {
            int f = f0 + ff;
            float4 w0 = *(const float4*)(Wc + (size_t)f * 64 + g4);
            float4 w1 = *(const float4*)(Wc + 4096u + (size_t)f * 64 + g4);
            float4 w2 = *(const float4*)(Wc + 8192u + (size_t)f * 64 + g4);
#pragma unroll
            for (int rr = 0; rr < 4; ++rr) {
                float a0 = t0s[(r0 + rr) * 17 + ff];
                float a1 = t1s[(r0 + rr) * 17 + ff];
                float a2 = t2s[(r0 + rr) * 17 + ff];
                acc[rr][0] += a0 * w0.x + a1 * w1.x + a2 * w2.x;
                acc[rr][1] += a0 * w0.y + a1 * w1.y + a2 * w2.y;
                acc[rr][2] += a0 * w0.z + a1 * w1.z + a2 * w2.z;
                acc[rr][3] += a0 * w0.w + a1 * w1.w + a2 * w2.w;
            }
        }
    }
    float4 bcv = *(const float4*)(bc + g4);
#pragma unroll
    for (int rr = 0; rr < 4; ++rr) {
        size_t r = rbase + r0 + rr;
        float4 v;
        v.x = fmaxf(acc[rr][0] + bcv.x, 0.f);
        v.y = fmaxf(acc[rr][1] + bcv.y, 0.f);
        v.z = fmaxf(acc[rr][2] + bcv.z, 0.f);
        v.w = fmaxf(acc[rr][3] + bcv.w, 0.f);
        *(float4*)(Xh + r * 64 + g4) = v;
    }
}

// fused time-conv + residual conv + relu + LayerNorm + output transpose
// thread = (o, all 16 t); waves quarter the K range; xh[g][20] b128 broadcasts
__global__ __launch_bounds__(256) void k_out(const float* __restrict__ X,
                                             const float* __restrict__ Xh,
                                             const float* __restrict__ WtT,
                                             const float* __restrict__ WrT,
                                             const float* __restrict__ bt,
                                             const float* __restrict__ br,
                                             const float* __restrict__ gamma,
                                             const float* __restrict__ beta,
                                             float* __restrict__ out) {
    __shared__ float xh[64 * 20];   // [g][slot], slot = t+1, slots 0,17..19 zero
    __shared__ float xl[64 * 16];   // [f][t]
    __shared__ float red[4160];     // 4*16*64 partials; reused as z[t*65+o]
    int bn = blockIdx.x;
    int b = bn >> 9, n = bn & 511;
    int tid = threadIdx.x;
    int o = tid & 63, q = tid >> 6;
    // zero halo slots: each thread zeroes one
    {
        int g = tid & 63, s4 = tid >> 6;
        int slot = (s4 == 0) ? 0 : 16 + s4;   // 0,17,18,19
        xh[g * 20 + slot] = 0.f;
    }
#pragma unroll
    for (int k = 0; k < 4; ++k) {
        int idx = tid + 256 * k;
        int t = idx >> 6, g = idx & 63;
        xh[g * 20 + t + 1] = Xh[((size_t)b * 16 + t) * 32768 + (size_t)n * 64 + g];
        xl[idx] = X[(size_t)bn * 1024 + idx];   // idx = f*16+t
    }
    __syncthreads();
    float acc[16];
#pragma unroll
    for (int k = 0; k < 16; ++k) acc[k] = 0.f;
    // temporal conv over this wave's g-quarter
    for (int gi = 0; gi < 16; ++gi) {
        int g = q * 16 + gi;
        const float4* xp = (const float4*)(xh + g * 20);
        float4 xa = xp[0], xb = xp[1], xc = xp[2], xd = xp[3], xe = xp[4];
        float xs[20] = {xa.x, xa.y, xa.z, xa.w, xb.x, xb.y, xb.z, xb.w,
                        xc.x, xc.y, xc.z, xc.w, xd.x, xd.y, xd.z, xd.w,
                        xe.x, xe.y, xe.z, xe.w};
        float w0 = WtT[(g * 3 + 0) * 64 + o];
        float w1 = WtT[(g * 3 + 1) * 64 + o];
        float w2 = WtT[(g * 3 + 2) * 64 + o];
#pragma unroll
        for (int tt = 0; tt < 16; ++tt)
            acc[tt] += xs[tt] * w0 + xs[tt + 1] * w1 + xs[tt + 2] * w2;
    }
    // residual conv over this wave's f-quarter
    for (int fi = 0; fi < 16; ++fi) {
        int f = q * 16 + fi;
        const float4* xp = (const float4*)(xl + f * 16);
        float4 xa = xp[0], xb = xp[1], xc = xp[2], xd = xp[3];
        float xs[16] = {xa.x, xa.y, xa.z, xa.w, xb.x, xb.y, xb.z, xb.w,
                        xc.x, xc.y, xc.z, xc.w, xd.x, xd.y, xd.z, xd.w};
        float w = WrT[f * 64 + o];
#pragma unroll
        for (int tt = 0; tt < 16; ++tt) acc[tt] += xs[tt] * w;
    }
    // cross-wave reduce
#pragma unroll
    for (int tt = 0; tt < 16; ++tt) red[q * 1024 + tt * 64 + o] = acc[tt];
    __syncthreads();
    float bsum = bt[o] + br[o];
    float go = gamma[o], bo = beta[o];
    float zv4[4];
#pragma unroll
    for (int tt = 0; tt < 4; ++tt) {
        int t = q * 4 + tt;
        float s = bsum;
#pragma unroll
        for (int qq = 0; qq < 4; ++qq) s += red[qq * 1024 + t * 64 + o];
        zv4[tt] = fmaxf(s, 0.f);
    }
    __syncthreads();    // before reusing red as z
#pragma unroll
    for (int tt = 0; tt < 4; ++tt) {
        int t = q * 4 + tt;
        float zv = zv4[tt];
        float s = zv, sq = zv * zv;
        for (int off = 32; off; off >>= 1) {
            s += __shfl_xor(s, off);
            sq += __shfl_xor(sq, off);
        }
        float mu = s * (1.f / 64.f);
        float var = sq * (1.f / 64.f) - mu * mu;
        red[t * 65 + o] = (zv - mu) * rsqrtf(var + 1e-5f) * go + bo;
    }
    __syncthreads();
#pragma unroll
    for (int k = 0; k < 4; ++k) {
        int i = tid + 256 * k;               // i = o*16 + t
        out[(size_t)bn * 1024 + i] = red[(i & 15) * 65 + (i >> 4)];
    }
}

extern "C" void kernel_launch(void* const* d_in, const int* in_sizes, int n_in,
                              void* d_out, int out_size, void* d_ws, size_t ws_size,
                              hipStream_t stream) {
    const float* X     = (const float*)d_in[0];
    const int*   ei    = (const int*)d_in[1];
    const float* U1    = (const float*)d_in[2];
    const float* U2    = (const float*)d_in[3];
    const float* U3    = (const float*)d_in[4];
    const float* be    = (const float*)d_in[5];
    const float* Ve    = (const float*)d_in[6];
    const float* Ws1   = (const float*)d_in[7];
    const float* Ws2   = (const float*)d_in[8];
    const float* Ws3   = (const float*)d_in[9];
    const float* bs    = (const float*)d_in[10];
    const float* Vs    = (const float*)d_in[11];
    const float* Wc    = (const float*)d_in[12];
    const float* bc    = (const float*)d_in[13];
    const float* Wt    = (const float*)d_in[14];
    const float* bt    = (const float*)d_in[15];
    const float* Wr    = (const float*)d_in[16];
    const float* br    = (const float*)d_in[17];
    const float* gamma = (const float*)d_in[18];
    const float* beta  = (const float*)d_in[19];

    float* ws = (float*)d_ws;
    float* Tx0    = ws + TX0_OFF;
    float* Tx1    = ws + TX1_OFF;
    float* Tx2    = ws + TX2_OFF;
    float* Xh     = ws + XHAT_OFF;
    float* Xt     = ws + XT_OFF;     // shares XHAT (dead before k_cheb)
    float* ST     = ws + ST_OFF;     // shares TX1 (dead before k_prop1)
    float* sigT   = ws + SIGT_OFF;   // shares TX2 (dead before k_prop2)
    float* bsT    = ws + BST_OFF;
    float* Et     = ws + ET_OFF;
    float* part   = ws + PART_OFF;
    float* rhs_t  = ws + RHST_OFF;
    float* lhs_s  = ws + LHSS_OFF;
    float* rhs_sn = ws + RHSSN_OFF;
    float* diagS  = ws + DIAGS_OFF;
    float* wS     = ws + WSATT_OFF;
    float* csr_w  = ws + CSRW_OFF;
    float* WtT    = ws + WTT_OFF;
    float* WrT    = ws + WRT_OFF;
    float* dis    = ws + DIS_OFF;

    int* ib        = (int*)(ws + FEND);
    int* row_start = ib;                  // 513 (pad to 516)
    int* csr_col   = ib + 516;            // NE
    int* csr_row   = csr_col + NE;        // NE
    int* counts    = csr_row + NE;        // 64*512

    // graph prep (parallel, deterministic)
    k_hist<<<64, 256, 0, stream>>>(ei, counts);
    k_scan2<<<1, 512, 0, stream>>>(counts, dis, row_start);
    k_fill2<<<64, 256, 0, stream>>>(ei, counts, row_start, dis, csr_col, csr_row, csr_w);

    // weight transposes (independent)
    k_wprep<<<64, 256, 0, stream>>>(Wt, Wr, WtT, WrT);
    k_bst<<<dim3(8, 8), 256, 0, stream>>>(bs, bsT);

    // temporal attention
    k_lhs1_partial<<<32, 256, 0, stream>>>(X, U1, part);
    k_rhs_t<<<128, 256, 0, stream>>>(X, U3, rhs_t);
    k_temporal<<<4, 256, 0, stream>>>(part, rhs_t, U2, be, Ve, Et);
    k_xt<<<512, 256, 0, stream>>>(X, Et, Xt);

    // spatial attention
    k_spat<<<2048, 64, 0, stream>>>(Xt, Ws1, Ws2, Ws3, lhs_s, rhs_sn);
    k_sigT<<<4096, 256, 0, stream>>>(lhs_s, rhs_sn, bsT, sigT);
    k_gemm_s<<<dim3(8, 8, 4), 256, 0, stream>>>(sigT, Vs, ST);
    k_softmax_s<<<2048, 256, 0, stream>>>(ST, diagS);
    k_wS<<<256, 256, 0, stream>>>(csr_col, csr_row, csr_w, ST, wS);

    // chebyshev conv
    k_tx0<<<2048, 256, 0, stream>>>(X, diagS, Tx0);
    k_prop1<<<32768, 64, 0, stream>>>(Tx0, wS, csr_col, row_start, Tx1);
    k_prop2<<<32768, 64, 0, stream>>>(Tx1, Tx0, csr_w, csr_col, row_start, Tx2);
    k_cheb<<<512, 256, 0, stream>>>(Tx0, Tx1, Tx2, Wc, bc, Xh);

    // time conv + residual + LN + transpose
    k_out<<<2048, 256, 0, stream>>>(X, Xh, WtT, WrT, bt, br, gamma, beta, (float*)d_out);
}

// Round 5
// 203.565 us; speedup vs baseline: 2.3836x; 1.3313x over previous
//
#include <hip/hip_runtime.h>
#include <math.h>

#define NB 4
#define NV 512
#define NF 64
#define NT 16
#define NE 16384

// ---------------- workspace layout (float offsets) ----------------
// Tx* and Xh are (B,N,F,T)/(B,N,G,T) now. ST shares TX1, sigT shares TX2,
// Xt shares XHAT (verified dead-lifetime overlaps).
#define TX1_OFF    2097152u    // 2097152  (also ST until k_wS)
#define TX2_OFF    4194304u    // 2097152  (also sigT until k_gemm_s)
#define XHAT_OFF   6291456u    // 2097152  (also Xt until k_spat)
#define ST_OFF     TX1_OFF
#define SIGT_OFF   TX2_OFF
#define XT_OFF     XHAT_OFF
#define BST_OFF    8388608u    // bs transposed 262144
#define ET_OFF     8650752u    // (B,16,16) 1024
#define PART_OFF   8651776u    // lhs1 partials 4*8*1024 = 32768
#define RHST_OFF   8684544u    // rhs_t (B,N,T) 32768
#define LHSS_OFF   8717312u    // lhs_s (B,N,T) 32768
#define RHSSN_OFF  8750080u    // rhs_s stored (B,N,T) 32768
#define DIAGS_OFF  8782848u    // (B,N) 2048
#define WSATT_OFF  8784896u    // wS (B,E) 65536
#define CSRW_OFF   8850432u    // 16384
#define WTT_OFF    8866816u    // 12288
#define WRT_OFF    8879104u    // 4096
#define DIS_OFF    8883200u    // 512
#define FEND       8883712u    // floats; ints live after this

// ============ graph prep (parallel, deterministic edge-id order) ============
__global__ void k_hist(const int* __restrict__ row, int* __restrict__ counts) {
    __shared__ int h[512];
    int c = blockIdx.x, i = threadIdx.x;
    h[i] = 0; h[i + 256] = 0;
    __syncthreads();
    atomicAdd(&h[row[c * 256 + i]], 1);
    __syncthreads();
    counts[c * 512 + i] = h[i];
    counts[c * 512 + i + 256] = h[i + 256];
}

__global__ void k_scan2(int* __restrict__ counts, float* __restrict__ dis,
                        int* __restrict__ row_start) {
    __shared__ int sc[512];
    int r = threadIdx.x;
    int sum = 0;
    for (int c = 0; c < 64; ++c) {
        int v = counts[c * 512 + r];
        counts[c * 512 + r] = sum;    // exclusive chunk base for this row
        sum += v;
    }
    dis[r] = sum > 0 ? 1.0f / sqrtf((float)sum) : 0.0f;
    sc[r] = sum;
    __syncthreads();
    for (int off = 1; off < 512; off <<= 1) {
        int v = sc[r];
        int add = (r >= off) ? sc[r - off] : 0;
        __syncthreads();
        sc[r] = v + add;
        __syncthreads();
    }
    int incl = sc[r];
    row_start[r] = incl - sum;
    if (r == 511) row_start[512] = incl;
}

__global__ void k_fill2(const int* __restrict__ ei, const int* __restrict__ counts,
                        const int* __restrict__ row_start, const float* __restrict__ dis,
                        int* __restrict__ csr_col, int* __restrict__ csr_row,
                        float* __restrict__ csr_w) {
    __shared__ int rowL[256];
    int c = blockIdx.x, i = threadIdx.x;
    int e = c * 256 + i;
    int r = ei[e];
    int col = ei[NE + e];
    rowL[i] = r;
    __syncthreads();
    int rank = 0;
    for (int j = 0; j < 256; ++j)
        if (j < i && rowL[j] == r) rank++;
    int pos = row_start[r] + counts[c * 512 + r] + rank;
    csr_col[pos] = col;
    csr_row[pos] = r;
    csr_w[pos] = -dis[r] * dis[col];
}

// ============ weight transposes ============
__global__ void k_wprep(const float* __restrict__ Wt, const float* __restrict__ Wr,
                        float* __restrict__ WtT, float* __restrict__ WrT) {
    int idx = blockIdx.x * 256 + threadIdx.x;
    if (idx < 12288) {
        int o = idx & 63, gd = idx >> 6;      // gd = g*3+dt
        int g = gd / 3, dt = gd - g * 3;
        WtT[idx] = Wt[(o * 64 + g) * 3 + dt];
    } else if (idx < 16384) {
        int i2 = idx - 12288;
        int o = i2 & 63, f = i2 >> 6;
        WrT[i2] = Wr[o * 64 + f];
    }
}

__global__ void k_bst(const float* __restrict__ bs, float* __restrict__ bsT) {
    __shared__ float tile[64][65];
    int r0 = blockIdx.y * 64, c0 = blockIdx.x * 64;
    int c = threadIdx.x & 63, rq = threadIdx.x >> 6;
    for (int k = 0; k < 16; ++k) {
        int r = rq * 16 + k;
        tile[r][c] = bs[(r0 + r) * 512 + c0 + c];
    }
    __syncthreads();
    int r2 = threadIdx.x & 63;
    for (int k = 0; k < 16; ++k) {
        int c2 = rq * 16 + k;
        bsT[(size_t)(c0 + c2) * 512 + r0 + r2] = tile[r2][c2];
    }
}

// ============ temporal attention ============
__global__ void k_lhs1_partial(const float* __restrict__ X, const float* __restrict__ U1,
                               float* __restrict__ part) {
    int b = blockIdx.x >> 3, g = blockIdx.x & 7;
    int tid = threadIdx.x;
    float acc[4] = {0.f, 0.f, 0.f, 0.f};
    const float* Xb = X + (size_t)b * NV * 1024;
    int n0 = g * 64;
    for (int nn = 0; nn < 64; ++nn) {
        int n = n0 + nn;
        float u = U1[n];
        const float* xp = Xb + (size_t)n * 1024;
#pragma unroll
        for (int k = 0; k < 4; ++k) acc[k] += xp[tid + 256 * k] * u;
    }
#pragma unroll
    for (int k = 0; k < 4; ++k) part[(size_t)(b * 8 + g) * 1024 + tid + 256 * k] = acc[k];
}

__global__ void k_rhs_t(const float* __restrict__ X, const float* __restrict__ U3,
                        float* __restrict__ rhs) {
    int gid = blockIdx.x * 256 + threadIdx.x;
    int t = gid & 15, n = (gid >> 4) & 511, b = gid >> 13;
    const float* xp = X + ((size_t)(b * 512 + n)) * 1024 + t;
    float a = 0.f;
#pragma unroll
    for (int f = 0; f < 64; ++f) a += U3[f] * xp[f * 16];
    rhs[gid] = a;
}

__global__ void k_temporal(const float* __restrict__ part, const float* __restrict__ rhs_g,
                           const float* __restrict__ U2, const float* __restrict__ be,
                           const float* __restrict__ Ve, float* __restrict__ Et) {
    __shared__ float lhs1[1024];
    __shared__ float rhsL[8192];
    __shared__ float M[1024];
    __shared__ float Esig[256];
    __shared__ float Et0[256];
    __shared__ float red[32];
    int b = blockIdx.x, tid = threadIdx.x;
#pragma unroll
    for (int k = 0; k < 4; ++k) {
        int idx = tid + 256 * k;
        float s = 0.f;
        for (int g = 0; g < 8; ++g) s += part[(size_t)(b * 8 + g) * 1024 + idx];
        lhs1[idx] = s;
    }
    for (int k = 0; k < 32; ++k) rhsL[tid + 256 * k] = rhs_g[(size_t)b * 8192 + tid + 256 * k];
    __syncthreads();
    {
        float acc[4] = {0.f, 0.f, 0.f, 0.f};
        int fA[4], tA[4];
#pragma unroll
        for (int k = 0; k < 4; ++k) { int idx = tid + 256 * k; fA[k] = idx >> 4; tA[k] = idx & 15; }
        for (int n = 0; n < 512; ++n) {
#pragma unroll
            for (int k = 0; k < 4; ++k) acc[k] += U2[fA[k] * 512 + n] * rhsL[n * 16 + tA[k]];
        }
#pragma unroll
        for (int k = 0; k < 4; ++k) M[tid + 256 * k] = acc[k];
    }
    __syncthreads();
    {
        int t1 = tid >> 4, t2 = tid & 15;
        float s = 0.f;
        for (int f = 0; f < 64; ++f) s += lhs1[f * 16 + t1] * M[f * 16 + t2];
        s += be[t1 * 16 + t2];
        Esig[tid] = 1.f / (1.f + expf(-s));
    }
    __syncthreads();
    {
        int t1 = tid >> 4, t2 = tid & 15;
        float s = 0.f;
        for (int k = 0; k < 16; ++k) s += Ve[t1 * 16 + k] * Esig[k * 16 + t2];
        Et0[tid] = s;
    }
    __syncthreads();
    if (tid < 16) {
        float m = -1e30f;
        for (int k = 0; k < 16; ++k) m = fmaxf(m, Et0[k * 16 + tid]);
        float s = 0.f;
        for (int k = 0; k < 16; ++k) s += expf(Et0[k * 16 + tid] - m);
        red[tid] = m; red[16 + tid] = 1.f / s;
    }
    __syncthreads();
    {
        int t2 = tid & 15;
        Et[b * 256 + tid] = expf(Et0[tid] - red[t2]) * red[16 + t2];
    }
}

// ============ Xt = X @ Et ============
__global__ void k_xt(const float* __restrict__ X, const float* __restrict__ Et,
                     float* __restrict__ Xt) {
    __shared__ float EtL[256];
    int tid = threadIdx.x;
    int b = blockIdx.x >> 7;
    size_t base = (size_t)blockIdx.x * 256 + tid;
    EtL[tid] = Et[b * 256 + tid];
    __syncthreads();
    const float4* xp = (const float4*)(X + base * 16);
    float4 a0 = xp[0], a1 = xp[1], a2 = xp[2], a3 = xp[3];
    float x[16] = {a0.x, a0.y, a0.z, a0.w, a1.x, a1.y, a1.z, a1.w,
                   a2.x, a2.y, a2.z, a2.w, a3.x, a3.y, a3.z, a3.w};
    float o[16];
#pragma unroll
    for (int t = 0; t < 16; ++t) {
        float s = 0.f;
#pragma unroll
        for (int tp = 0; tp < 16; ++tp) s += x[tp] * EtL[tp * 16 + t];
        o[t] = s;
    }
    float4* op = (float4*)(Xt + base * 16);
    op[0] = make_float4(o[0], o[1], o[2], o[3]);
    op[1] = make_float4(o[4], o[5], o[6], o[7]);
    op[2] = make_float4(o[8], o[9], o[10], o[11]);
    op[3] = make_float4(o[12], o[13], o[14], o[15]);
}

// ============ spatial attention small parts ============
__global__ void k_spat(const float* __restrict__ Xt, const float* __restrict__ Ws1,
                       const float* __restrict__ Ws2, const float* __restrict__ Ws3,
                       float* __restrict__ lhs_s, float* __restrict__ rhs_sn) {
    __shared__ float xl[1024];
    __shared__ float l1[64];
    int bn = blockIdx.x, tid = threadIdx.x;
    const float* xp = Xt + (size_t)bn * 1024;
    for (int k = 0; k < 16; ++k) xl[tid + 64 * k] = xp[tid + 64 * k];
    __syncthreads();
    float s = 0.f;
#pragma unroll
    for (int t = 0; t < 16; ++t) s += xl[tid * 16 + t] * Ws1[t];
    l1[tid] = s;
    __syncthreads();
    if (tid < 16) {
        float a = 0.f;
        for (int f = 0; f < 64; ++f) a += l1[f] * Ws2[f * 16 + tid];
        lhs_s[(size_t)bn * 16 + tid] = a;
    } else if (tid < 32) {
        int t = tid - 16;
        float a = 0.f;
        for (int f = 0; f < 64; ++f) a += Ws3[f] * xl[f * 16 + t];
        rhs_sn[(size_t)bn * 16 + t] = a;
    }
}

// grid: B*N*N/256 = 4096 blocks (b = gid>>18)
__global__ void k_sigT(const float* __restrict__ lhs_s, const float* __restrict__ rhs_sn,
                       const float* __restrict__ bsT, float* __restrict__ sigT) {
    int gid = blockIdx.x * 256 + threadIdx.x;
    int k = gid & 511, j = (gid >> 9) & 511, b = gid >> 18;
    const float4* lp = (const float4*)(lhs_s + (size_t)(b * 512 + k) * 16);
    const float4* rp = (const float4*)(rhs_sn + (size_t)(b * 512 + j) * 16);
    float s = 0.f;
#pragma unroll
    for (int q = 0; q < 4; ++q) {
        float4 a = lp[q], c = rp[q];
        s += a.x * c.x + a.y * c.y + a.z * c.z + a.w * c.w;
    }
    s += bsT[(size_t)j * 512 + k];
    sigT[gid] = 1.f / (1.f + expf(-s));
}

// S0T[b][j][i] = sum_k sigT[b][j][k] * Vs[i][k]
__global__ __launch_bounds__(256) void k_gemm_s(const float* __restrict__ sigT,
                                                const float* __restrict__ Vs,
                                                float* __restrict__ S0T) {
    __shared__ float As[64 * 33];
    __shared__ float Bs[64 * 33];
    int bI = blockIdx.x, bJ = blockIdx.y, b = blockIdx.z;
    int tid = threadIdx.x, tx = tid & 15, ty = tid >> 4;
    float acc[4][4] = {};
    const float* Ab = sigT + ((size_t)b * 512 + bJ * 64) * 512;
    const float* Bb = Vs + (size_t)bI * 64 * 512;
    for (int k0 = 0; k0 < 512; k0 += 32) {
#pragma unroll
        for (int p = 0; p < 2; ++p) {
            int idx = tid + 256 * p;
            int row = idx >> 3, kk = (idx & 7) * 4;
            float4 a = *(const float4*)(Ab + (size_t)row * 512 + k0 + kk);
            As[row * 33 + kk] = a.x; As[row * 33 + kk + 1] = a.y;
            As[row * 33 + kk + 2] = a.z; As[row * 33 + kk + 3] = a.w;
            float4 v = *(const float4*)(Bb + (size_t)row * 512 + k0 + kk);
            Bs[row * 33 + kk] = v.x; Bs[row * 33 + kk + 1] = v.y;
            Bs[row * 33 + kk + 2] = v.z; Bs[row * 33 + kk + 3] = v.w;
        }
        __syncthreads();
#pragma unroll
        for (int kk = 0; kk < 32; ++kk) {
            float a[4], bb[4];
#pragma unroll
            for (int q = 0; q < 4; ++q) a[q] = As[(ty * 4 + q) * 33 + kk];
#pragma unroll
            for (int q = 0; q < 4; ++q) bb[q] = Bs[(tx * 4 + q) * 33 + kk];
#pragma unroll
            for (int y = 0; y < 4; ++y)
#pragma unroll
                for (int x = 0; x < 4; ++x) acc[y][x] += a[y] * bb[x];
        }
        __syncthreads();
    }
    float* Cb = S0T + ((size_t)b * 512 + bJ * 64) * 512 + bI * 64;
#pragma unroll
    for (int y = 0; y < 4; ++y) {
        int j = ty * 4 + y;
        *(float4*)(Cb + (size_t)j * 512 + tx * 4) =
            make_float4(acc[y][0], acc[y][1], acc[y][2], acc[y][3]);
    }
}

// softmax over i (contiguous) in-place; extract diagonal
__global__ void k_softmax_s(float* __restrict__ ST, float* __restrict__ diagS) {
    __shared__ float red[4];
    int bj = blockIdx.x;
    int b = bj >> 9, j = bj & 511;
    float* row = ST + (size_t)bj * 512;
    int tid = threadIdx.x;
    float v0 = row[tid], v1 = row[tid + 256];
    float m = fmaxf(v0, v1);
    for (int off = 32; off; off >>= 1) m = fmaxf(m, __shfl_xor(m, off));
    if ((tid & 63) == 0) red[tid >> 6] = m;
    __syncthreads();
    m = fmaxf(fmaxf(red[0], red[1]), fmaxf(red[2], red[3]));
    __syncthreads();
    float e0 = expf(v0 - m), e1 = expf(v1 - m);
    float s = e0 + e1;
    for (int off = 32; off; off >>= 1) s += __shfl_xor(s, off);
    if ((tid & 63) == 0) red[tid >> 6] = s;
    __syncthreads();
    s = red[0] + red[1] + red[2] + red[3];
    float inv = 1.f / s;
    float r0 = e0 * inv, r1 = e1 * inv;
    row[tid] = r0;
    row[tid + 256] = r1;
    if (j < 256) { if (tid == j) diagS[b * 512 + j] = r0; }
    else { if (tid == j - 256) diagS[b * 512 + j] = r1; }
}

// wS[b][pos] = csr_w[pos] * S[b,row,col] * diagS[b,col]  (diagS folded for prop1)
__global__ void k_wS(const int* __restrict__ csr_col, const int* __restrict__ csr_row,
                     const float* __restrict__ csr_w, const float* __restrict__ ST,
                     const float* __restrict__ diagS, float* __restrict__ wS) {
    int gid = blockIdx.x * 256 + threadIdx.x;
    int pos = gid & (NE - 1), b = gid >> 14;
    int c = csr_col[pos], r = csr_row[pos];
    wS[gid] = csr_w[pos] * ST[((size_t)(b * 512 + c)) * 512 + r] * diagS[b * 512 + c];
}

// Tx1[b,i,:,:] = sum_edges wS[b,p] * X[b,col,:,:]   (diagS already folded in wS)
// one (b,i) row per 256-thread block; XCD-swizzled so a b-slice stays on one L2
__global__ __launch_bounds__(256) void k_prop1(const float* __restrict__ X,
                                               const float* __restrict__ wS,
                                               const int* __restrict__ csr_col,
                                               const int* __restrict__ row_start,
                                               float* __restrict__ Tx1) {
    int blk = ((blockIdx.x & 7) << 8) + (blockIdx.x >> 3);   // 2048 % 8 == 0
    int b = blk >> 9, i = blk & 511;
    int tid = threadIdx.x;
    int s = row_start[i], e2 = row_start[i + 1];
    const float4* Xb = (const float4*)(X + (size_t)b * 512 * 1024);
    const float* wb = wS + (size_t)b * NE;
    float4 acc = make_float4(0.f, 0.f, 0.f, 0.f);
    for (int p = s; p < e2; ++p) {
        int col = csr_col[p];
        float w = wb[p];
        float4 v = Xb[col * 256 + tid];
        acc.x += w * v.x; acc.y += w * v.y; acc.z += w * v.z; acc.w += w * v.w;
    }
    *(float4*)(Tx1 + (size_t)blk * 1024 + tid * 4) = acc;
}

// Tx2[b,i] = 2 * sum_edges csr_w[p]*Tx1[b,col] - diagS[b,i]*X[b,i]
__global__ __launch_bounds__(256) void k_prop2(const float* __restrict__ Tx1,
                                               const float* __restrict__ X,
                                               const float* __restrict__ diagS,
                                               const float* __restrict__ csr_w,
                                               const int* __restrict__ csr_col,
                                               const int* __restrict__ row_start,
                                               float* __restrict__ Tx2) {
    int blk = ((blockIdx.x & 7) << 8) + (blockIdx.x >> 3);
    int b = blk >> 9, i = blk & 511;
    int tid = threadIdx.x;
    int s = row_start[i], e2 = row_start[i + 1];
    const float4* T1b = (const float4*)(Tx1 + (size_t)b * 512 * 1024);
    float4 acc = make_float4(0.f, 0.f, 0.f, 0.f);
    for (int p = s; p < e2; ++p) {
        int col = csr_col[p];
        float w = csr_w[p];
        float4 v = T1b[col * 256 + tid];
        acc.x += w * v.x; acc.y += w * v.y; acc.z += w * v.z; acc.w += w * v.w;
    }
    float ds = diagS[blk];
    float4 x0 = *(const float4*)(X + (size_t)blk * 1024 + tid * 4);
    float4 o;
    o.x = 2.f * acc.x - ds * x0.x;
    o.y = 2.f * acc.y - ds * x0.y;
    o.z = 2.f * acc.z - ds * x0.z;
    o.w = 2.f * acc.w - ds * x0.w;
    *(float4*)(Tx2 + (size_t)blk * 1024 + tid * 4) = o;
}

// Xh[b,n,g,t] = relu(sum_f W0[f,g]*ds*X[b,n,f,t] + W1[f,g]*Tx1[..] + W2[f,g]*Tx2[..] + bc[g])
__global__ __launch_bounds__(256) void k_cheb(const float* __restrict__ X,
                                              const float* __restrict__ Tx1,
                                              const float* __restrict__ Tx2,
                                              const float* __restrict__ diagS,
                                              const float* __restrict__ Wc,
                                              const float* __restrict__ bc,
                                              float* __restrict__ Xh) {
    __shared__ float t0s[1024], t1s[1024], t2s[1024];   // [f][t]
    int bn = blockIdx.x;
    int tid = threadIdx.x;
    float ds = diagS[bn];
    float4 v0 = ((const float4*)(X + (size_t)bn * 1024))[tid];
    v0.x *= ds; v0.y *= ds; v0.z *= ds; v0.w *= ds;
    ((float4*)t0s)[tid] = v0;
    ((float4*)t1s)[tid] = ((const float4*)(Tx1 + (size_t)bn * 1024))[tid];
    ((float4*)t2s)[tid] = ((const float4*)(Tx2 + (size_t)bn * 1024))[tid];
    __syncthreads();
    int g = tid >> 2, t4 = (tid & 3) * 4;
    float bcg = bc[g];
    float4 acc = make_float4(bcg, bcg, bcg, bcg);
    for (int f = 0; f < 64; ++f) {
        float w0 = Wc[f * 64 + g];
        float w1 = Wc[4096 + f * 64 + g];
        float w2 = Wc[8192 + f * 64 + g];
        float4 a0 = *(const float4*)(t0s + f * 16 + t4);
        float4 a1 = *(const float4*)(t1s + f * 16 + t4);
        float4 a2 = *(const float4*)(t2s + f * 16 + t4);
        acc.x += w0 * a0.x + w1 * a1.x + w2 * a2.x;
        acc.y += w0 * a0.y + w1 * a1.y + w2 * a2.y;
        acc.z += w0 * a0.z + w1 * a1.z + w2 * a2.z;
        acc.w += w0 * a0.w + w1 * a1.w + w2 * a2.w;
    }
    float4 o;
    o.x = fmaxf(acc.x, 0.f); o.y = fmaxf(acc.y, 0.f);
    o.z = fmaxf(acc.z, 0.f); o.w = fmaxf(acc.w, 0.f);
    *(float4*)(Xh + (size_t)bn * 1024 + g * 16 + t4) = o;
}

// fused time-conv + residual conv + relu + LayerNorm + output transpose
// Xh now (b,n,g,t) -> fully coalesced row load
__global__ __launch_bounds__(256) void k_out(const float* __restrict__ X,
                                             const float* __restrict__ Xh,
                                             const float* __restrict__ WtT,
                                             const float* __restrict__ WrT,
                                             const float* __restrict__ bt,
                                             const float* __restrict__ br,
                                             const float* __restrict__ gamma,
                                             const float* __restrict__ beta,
                                             float* __restrict__ out) {
    __shared__ float xh[64 * 20];   // [g][slot], slot = t+1, slots 0,17..19 zero
    __shared__ float xl[64 * 16];   // [f][t]
    __shared__ float red[4160];     // 4*16*64 partials; reused as z[t*65+o]
    int bn = blockIdx.x;
    int tid = threadIdx.x;
    int o = tid & 63, q = tid >> 6;
    {
        int g = tid & 63, s4 = tid >> 6;
        int slot = (s4 == 0) ? 0 : 16 + s4;   // 0,17,18,19
        xh[g * 20 + slot] = 0.f;
    }
    {
        float4 v = ((const float4*)(Xh + (size_t)bn * 1024))[tid];
        int g = tid >> 2, t0 = (tid & 3) * 4;
        xh[g * 20 + t0 + 1] = v.x;
        xh[g * 20 + t0 + 2] = v.y;
        xh[g * 20 + t0 + 3] = v.z;
        xh[g * 20 + t0 + 4] = v.w;
        float4 u = ((const float4*)(X + (size_t)bn * 1024))[tid];
        *(float4*)(xl + tid * 4) = u;      // xl[f][t] same layout as X row
    }
    __syncthreads();
    float acc[16];
#pragma unroll
    for (int k = 0; k < 16; ++k) acc[k] = 0.f;
    // temporal conv over this wave's g-quarter
    for (int gi = 0; gi < 16; ++gi) {
        int g = q * 16 + gi;
        const float4* xp = (const float4*)(xh + g * 20);
        float4 xa = xp[0], xb = xp[1], xc = xp[2], xd = xp[3], xe = xp[4];
        float xs[20] = {xa.x, xa.y, xa.z, xa.w, xb.x, xb.y, xb.z, xb.w,
                        xc.x, xc.y, xc.z, xc.w, xd.x, xd.y, xd.z, xd.w,
                        xe.x, xe.y, xe.z, xe.w};
        float w0 = WtT[(g * 3 + 0) * 64 + o];
        float w1 = WtT[(g * 3 + 1) * 64 + o];
        float w2 = WtT[(g * 3 + 2) * 64 + o];
#pragma unroll
        for (int tt = 0; tt < 16; ++tt)
            acc[tt] += xs[tt] * w0 + xs[tt + 1] * w1 + xs[tt + 2] * w2;
    }
    // residual conv over this wave's f-quarter
    for (int fi = 0; fi < 16; ++fi) {
        int f = q * 16 + fi;
        const float4* xp = (const float4*)(xl + f * 16);
        float4 xa = xp[0], xb = xp[1], xc = xp[2], xd = xp[3];
        float xs[16] = {xa.x, xa.y, xa.z, xa.w, xb.x, xb.y, xb.z, xb.w,
                        xc.x, xc.y, xc.z, xc.w, xd.x, xd.y, xd.z, xd.w};
        float w = WrT[f * 64 + o];
#pragma unroll
        for (int tt = 0; tt < 16; ++tt) acc[tt] += xs[tt] * w;
    }
    // cross-wave reduce
#pragma unroll
    for (int tt = 0; tt < 16; ++tt) red[q * 1024 + tt * 64 + o] = acc[tt];
    __syncthreads();
    float bsum = bt[o] + br[o];
    float go = gamma[o], bo = beta[o];
    float zv4[4];
#pragma unroll
    for (int tt = 0; tt < 4; ++tt) {
        int t = q * 4 + tt;
        float s = bsum;
#pragma unroll
        for (int qq = 0; qq < 4; ++qq) s += red[qq * 1024 + t * 64 + o];
        zv4[tt] = fmaxf(s, 0.f);
    }
    __syncthreads();    // before reusing red as z
#pragma unroll
    for (int tt = 0; tt < 4; ++tt) {
        int t = q * 4 + tt;
        float zv = zv4[tt];
        float s = zv, sq = zv * zv;
        for (int off = 32; off; off >>= 1) {
            s += __shfl_xor(s, off);
            sq += __shfl_xor(sq, off);
        }
        float mu = s * (1.f / 64.f);
        float var = sq * (1.f / 64.f) - mu * mu;
        red[t * 65 + o] = (zv - mu) * rsqrtf(var + 1e-5f) * go + bo;
    }
    __syncthreads();
#pragma unroll
    for (int k = 0; k < 4; ++k) {
        int i = tid + 256 * k;               // i = o*16 + t
        out[(size_t)bn * 1024 + i] = red[(i & 15) * 65 + (i >> 4)];
    }
}

extern "C" void kernel_launch(void* const* d_in, const int* in_sizes, int n_in,
                              void* d_out, int out_size, void* d_ws, size_t ws_size,
                              hipStream_t stream) {
    const float* X     = (const float*)d_in[0];
    const int*   ei    = (const int*)d_in[1];
    const float* U1    = (const float*)d_in[2];
    const float* U2    = (const float*)d_in[3];
    const float* U3    = (const float*)d_in[4];
    const float* be    = (const float*)d_in[5];
    const float* Ve    = (const float*)d_in[6];
    const float* Ws1   = (const float*)d_in[7];
    const float* Ws2   = (const float*)d_in[8];
    const float* Ws3   = (const float*)d_in[9];
    const float* bs    = (const float*)d_in[10];
    const float* Vs    = (const float*)d_in[11];
    const float* Wc    = (const float*)d_in[12];
    const float* bc    = (const float*)d_in[13];
    const float* Wt    = (const float*)d_in[14];
    const float* bt    = (const float*)d_in[15];
    const float* Wr    = (const float*)d_in[16];
    const float* br    = (const float*)d_in[17];
    const float* gamma = (const float*)d_in[18];
    const float* beta  = (const float*)d_in[19];

    float* ws = (float*)d_ws;
    float* Tx1    = ws + TX1_OFF;
    float* Tx2    = ws + TX2_OFF;
    float* Xh     = ws + XHAT_OFF;
    float* Xt     = ws + XT_OFF;     // shares XHAT (dead before k_cheb)
    float* ST     = ws + ST_OFF;     // shares TX1 (dead before k_prop1)
    float* sigT   = ws + SIGT_OFF;   // shares TX2 (dead before k_prop2)
    float* bsT    = ws + BST_OFF;
    float* Et     = ws + ET_OFF;
    float* part   = ws + PART_OFF;
    float* rhs_t  = ws + RHST_OFF;
    float* lhs_s  = ws + LHSS_OFF;
    float* rhs_sn = ws + RHSSN_OFF;
    float* diagS  = ws + DIAGS_OFF;
    float* wS     = ws + WSATT_OFF;
    float* csr_w  = ws + CSRW_OFF;
    float* WtT    = ws + WTT_OFF;
    float* WrT    = ws + WRT_OFF;
    float* dis    = ws + DIS_OFF;

    int* ib        = (int*)(ws + FEND);
    int* row_start = ib;                  // 513 (pad to 516)
    int* csr_col   = ib + 516;            // NE
    int* csr_row   = csr_col + NE;        // NE
    int* counts    = csr_row + NE;        // 64*512

    // graph prep (parallel, deterministic)
    k_hist<<<64, 256, 0, stream>>>(ei, counts);
    k_scan2<<<1, 512, 0, stream>>>(counts, dis, row_start);
    k_fill2<<<64, 256, 0, stream>>>(ei, counts, row_start, dis, csr_col, csr_row, csr_w);

    // weight transposes (independent)
    k_wprep<<<64, 256, 0, stream>>>(Wt, Wr, WtT, WrT);
    k_bst<<<dim3(8, 8), 256, 0, stream>>>(bs, bsT);

    // temporal attention
    k_lhs1_partial<<<32, 256, 0, stream>>>(X, U1, part);
    k_rhs_t<<<128, 256, 0, stream>>>(X, U3, rhs_t);
    k_temporal<<<4, 256, 0, stream>>>(part, rhs_t, U2, be, Ve, Et);
    k_xt<<<512, 256, 0, stream>>>(X, Et, Xt);

    // spatial attention
    k_spat<<<2048, 64, 0, stream>>>(Xt, Ws1, Ws2, Ws3, lhs_s, rhs_sn);
    k_sigT<<<4096, 256, 0, stream>>>(lhs_s, rhs_sn, bsT, sigT);
    k_gemm_s<<<dim3(8, 8, 4), 256, 0, stream>>>(sigT, Vs, ST);
    k_softmax_s<<<2048, 256, 0, stream>>>(ST, diagS);
    k_wS<<<256, 256, 0, stream>>>(csr_col, csr_row, csr_w, ST, diagS, wS);

    // chebyshev conv (B,N,F,T layout; Tx0 folded into diagS*X)
    k_prop1<<<2048, 256, 0, stream>>>(X, wS, csr_col, row_start, Tx1);
    k_prop2<<<2048, 256, 0, stream>>>(Tx1, X, diagS, csr_w, csr_col, row_start, Tx2);
    k_cheb<<<2048, 256, 0, stream>>>(X, Tx1, Tx2, diagS, Wc, bc, Xh);

    // time conv + residual + LN + transpose
    k_out<<<2048, 256, 0, stream>>>(X, Xh, WtT, WrT, bt, br, gamma, beta, (float*)d_out);
}

// Round 7
// 177.545 us; speedup vs baseline: 2.7330x; 1.1466x over previous
//
#include <hip/hip_runtime.h>
#include <math.h>

#define NB 4
#define NV 512
#define NF 64
#define NT 16
#define NE 16384

// ---------------- workspace layout (float offsets) ----------------
#define TX1_OFF    2097152u    // 2097152  (also ST until k_wS)
#define TX2_OFF    4194304u    // 2097152  (also sigT until k_gemm_s)
#define XHAT_OFF   6291456u    // 2097152
#define ST_OFF     TX1_OFF
#define SIGT_OFF   TX2_OFF
#define BST_OFF    8388608u    // bs transposed 262144
#define ET_OFF     8650752u    // (B,16,16) 1024
#define PART_OFF   8651776u    // lhs1 partials 4*8*1024 = 32768
#define RHST_OFF   8684544u    // rhs_t (B,N,T) 32768
#define LHSS_OFF   8717312u    // lhs_s (B,N,T) 32768
#define RHSSN_OFF  8750080u    // rhs_s stored (B,N,T) 32768
#define DIAGS_OFF  8782848u    // (B,N) 2048
#define WSATT_OFF  8784896u    // wS (B,E) 65536
#define CSRW_OFF   8850432u    // 16384
#define WTT_OFF    8866816u    // 12288
#define WRT_OFF    8879104u    // 4096
#define DIS_OFF    8883200u    // 512
#define RHS3_OFF   8883712u    // rhs3 (B,N,T) 32768
#define EW1_OFF    8916480u    // (B,16) 64
#define FEND       8916544u    // floats; ints live after this

// ============ graph prep (parallel, deterministic edge-id order) ============
__global__ void k_hist(const int* __restrict__ row, int* __restrict__ counts) {
    __shared__ int h[512];
    int c = blockIdx.x, i = threadIdx.x;
    h[i] = 0; h[i + 256] = 0;
    __syncthreads();
    atomicAdd(&h[row[c * 256 + i]], 1);
    __syncthreads();
    counts[c * 512 + i] = h[i];
    counts[c * 512 + i + 256] = h[i + 256];
}

__global__ void k_scan2(int* __restrict__ counts, float* __restrict__ dis,
                        int* __restrict__ row_start) {
    __shared__ int sc[512];
    int r = threadIdx.x;
    int sum = 0;
    for (int c = 0; c < 64; ++c) {
        int v = counts[c * 512 + r];
        counts[c * 512 + r] = sum;    // exclusive chunk base for this row
        sum += v;
    }
    dis[r] = sum > 0 ? 1.0f / sqrtf((float)sum) : 0.0f;
    sc[r] = sum;
    __syncthreads();
    for (int off = 1; off < 512; off <<= 1) {
        int v = sc[r];
        int add = (r >= off) ? sc[r - off] : 0;
        __syncthreads();
        sc[r] = v + add;
        __syncthreads();
    }
    int incl = sc[r];
    row_start[r] = incl - sum;
    if (r == 511) row_start[512] = incl;
}

__global__ void k_fill2(const int* __restrict__ ei, const int* __restrict__ counts,
                        const int* __restrict__ row_start, const float* __restrict__ dis,
                        int* __restrict__ csr_col, int* __restrict__ csr_row,
                        float* __restrict__ csr_w) {
    __shared__ int rowL[256];
    int c = blockIdx.x, i = threadIdx.x;
    int e = c * 256 + i;
    int r = ei[e];
    int col = ei[NE + e];
    rowL[i] = r;
    __syncthreads();
    int rank = 0;
    for (int j = 0; j < 256; ++j)
        if (j < i && rowL[j] == r) rank++;
    int pos = row_start[r] + counts[c * 512 + r] + rank;
    csr_col[pos] = col;
    csr_row[pos] = r;
    csr_w[pos] = -dis[r] * dis[col];
}

// ============ weight transposes ============
__global__ void k_wprep(const float* __restrict__ Wt, const float* __restrict__ Wr,
                        float* __restrict__ WtT, float* __restrict__ WrT) {
    int idx = blockIdx.x * 256 + threadIdx.x;
    if (idx < 12288) {
        int o = idx & 63, gd = idx >> 6;      // gd = g*3+dt
        int g = gd / 3, dt = gd - g * 3;
        WtT[idx] = Wt[(o * 64 + g) * 3 + dt];
    } else if (idx < 16384) {
        int i2 = idx - 12288;
        int o = i2 & 63, f = i2 >> 6;
        WrT[i2] = Wr[o * 64 + f];
    }
}

__global__ void k_bst(const float* __restrict__ bs, float* __restrict__ bsT) {
    __shared__ float tile[64][65];
    int r0 = blockIdx.y * 64, c0 = blockIdx.x * 64;
    int c = threadIdx.x & 63, rq = threadIdx.x >> 6;
    for (int k = 0; k < 16; ++k) {
        int r = rq * 16 + k;
        tile[r][c] = bs[(r0 + r) * 512 + c0 + c];
    }
    __syncthreads();
    int r2 = threadIdx.x & 63;
    for (int k = 0; k < 16; ++k) {
        int c2 = rq * 16 + k;
        bsT[(size_t)(c0 + c2) * 512 + r0 + r2] = tile[r2][c2];
    }
}

// ============ temporal attention ============
__global__ void k_lhs1_partial(const float* __restrict__ X, const float* __restrict__ U1,
                               float* __restrict__ part) {
    int b = blockIdx.x >> 3, g = blockIdx.x & 7;
    int tid = threadIdx.x;
    float acc[4] = {0.f, 0.f, 0.f, 0.f};
    const float* Xb = X + (size_t)b * NV * 1024;
    int n0 = g * 64;
    for (int nn = 0; nn < 64; ++nn) {
        int n = n0 + nn;
        float u = U1[n];
        const float* xp = Xb + (size_t)n * 1024;
#pragma unroll
        for (int k = 0; k < 4; ++k) acc[k] += xp[tid + 256 * k] * u;
    }
#pragma unroll
    for (int k = 0; k < 4; ++k) part[(size_t)(b * 8 + g) * 1024 + tid + 256 * k] = acc[k];
}

// rhs[b,n,t] = sum_f U3[f]*X[b,n,f,t];  rhs3 same with Ws3
__global__ void k_rhs_t(const float* __restrict__ X, const float* __restrict__ U3,
                        const float* __restrict__ Ws3,
                        float* __restrict__ rhs, float* __restrict__ rhs3) {
    int gid = blockIdx.x * 256 + threadIdx.x;
    int t = gid & 15, n = (gid >> 4) & 511, b = gid >> 13;
    const float* xp = X + ((size_t)(b * 512 + n)) * 1024 + t;
    float a = 0.f, a3 = 0.f;
#pragma unroll
    for (int f = 0; f < 64; ++f) {
        float v = xp[f * 16];
        a += U3[f] * v;
        a3 += Ws3[f] * v;
    }
    rhs[gid] = a;
    rhs3[gid] = a3;
}

__global__ void k_temporal(const float* __restrict__ part, const float* __restrict__ rhs_g,
                           const float* __restrict__ U2, const float* __restrict__ be,
                           const float* __restrict__ Ve, const float* __restrict__ Ws1,
                           float* __restrict__ Et, float* __restrict__ ew1) {
    __shared__ float lhs1[1024];
    __shared__ float rhsL[8192];
    __shared__ float M[1024];
    __shared__ float Esig[256];
    __shared__ float Et0[256];
    __shared__ float red[32];
    __shared__ float EtL[256];
    int b = blockIdx.x, tid = threadIdx.x;
#pragma unroll
    for (int k = 0; k < 4; ++k) {
        int idx = tid + 256 * k;
        float s = 0.f;
        for (int g = 0; g < 8; ++g) s += part[(size_t)(b * 8 + g) * 1024 + idx];
        lhs1[idx] = s;
    }
    for (int k = 0; k < 32; ++k) rhsL[tid + 256 * k] = rhs_g[(size_t)b * 8192 + tid + 256 * k];
    __syncthreads();
    {
        float acc[4] = {0.f, 0.f, 0.f, 0.f};
        int fA[4], tA[4];
#pragma unroll
        for (int k = 0; k < 4; ++k) { int idx = tid + 256 * k; fA[k] = idx >> 4; tA[k] = idx & 15; }
        for (int n = 0; n < 512; ++n) {
#pragma unroll
            for (int k = 0; k < 4; ++k) acc[k] += U2[fA[k] * 512 + n] * rhsL[n * 16 + tA[k]];
        }
#pragma unroll
        for (int k = 0; k < 4; ++k) M[tid + 256 * k] = acc[k];
    }
    __syncthreads();
    {
        int t1 = tid >> 4, t2 = tid & 15;
        float s = 0.f;
        for (int f = 0; f < 64; ++f) s += lhs1[f * 16 + t1] * M[f * 16 + t2];
        s += be[t1 * 16 + t2];
        Esig[tid] = 1.f / (1.f + expf(-s));
    }
    __syncthreads();
    {
        int t1 = tid >> 4, t2 = tid & 15;
        float s = 0.f;
        for (int k = 0; k < 16; ++k) s += Ve[t1 * 16 + k] * Esig[k * 16 + t2];
        Et0[tid] = s;
    }
    __syncthreads();
    if (tid < 16) {
        float m = -1e30f;
        for (int k = 0; k < 16; ++k) m = fmaxf(m, Et0[k * 16 + tid]);
        float s = 0.f;
        for (int k = 0; k < 16; ++k) s += expf(Et0[k * 16 + tid] - m);
        red[tid] = m; red[16 + tid] = 1.f / s;
    }
    __syncthreads();
    {
        int t2 = tid & 15;
        float etv = expf(Et0[tid] - red[t2]) * red[16 + t2];
        Et[b * 256 + tid] = etv;
        EtL[tid] = etv;
    }
    __syncthreads();
    if (tid < 16) {
        float s = 0.f;
        for (int t = 0; t < 16; ++t) s += EtL[tid * 16 + t] * Ws1[t];
        ew1[b * 16 + tid] = s;     // ew1[tp] = sum_t Et[tp][t]*Ws1[t]
    }
}

// ============ spatial attention lhs/rhs directly from X (Xt eliminated) ============
__global__ __launch_bounds__(256) void k_spat2(const float* __restrict__ X,
                                               const float* __restrict__ ew1,
                                               const float* __restrict__ rhs3,
                                               const float* __restrict__ Et,
                                               const float* __restrict__ Ws2,
                                               float* __restrict__ lhs_s,
                                               float* __restrict__ rhs_sn) {
    int wv = threadIdx.x >> 6, lane = threadIdx.x & 63;
    int bn = blockIdx.x * 4 + wv;
    int b = bn >> 9;
    const float4* xp = (const float4*)(X + (size_t)bn * 1024 + lane * 16);
    float4 x0 = xp[0], x1 = xp[1], x2 = xp[2], x3 = xp[3];
    const float* e1 = ew1 + b * 16;
    float l1 = x0.x * e1[0] + x0.y * e1[1] + x0.z * e1[2] + x0.w * e1[3]
             + x1.x * e1[4] + x1.y * e1[5] + x1.z * e1[6] + x1.w * e1[7]
             + x2.x * e1[8] + x2.y * e1[9] + x2.z * e1[10] + x2.w * e1[11]
             + x3.x * e1[12] + x3.y * e1[13] + x3.z * e1[14] + x3.w * e1[15];
    const float4* wp = (const float4*)(Ws2 + lane * 16);
    float4 w0 = wp[0], w1 = wp[1], w2 = wp[2], w3 = wp[3];
    float p[16] = {l1 * w0.x, l1 * w0.y, l1 * w0.z, l1 * w0.w,
                   l1 * w1.x, l1 * w1.y, l1 * w1.z, l1 * w1.w,
                   l1 * w2.x, l1 * w2.y, l1 * w2.z, l1 * w2.w,
                   l1 * w3.x, l1 * w3.y, l1 * w3.z, l1 * w3.w};
#pragma unroll
    for (int off = 32; off; off >>= 1) {
#pragma unroll
        for (int k = 0; k < 16; ++k) p[k] += __shfl_xor(p[k], off);
    }
    if (lane == 0) {
        float4* lp = (float4*)(lhs_s + (size_t)bn * 16);
        lp[0] = make_float4(p[0], p[1], p[2], p[3]);
        lp[1] = make_float4(p[4], p[5], p[6], p[7]);
        lp[2] = make_float4(p[8], p[9], p[10], p[11]);
        lp[3] = make_float4(p[12], p[13], p[14], p[15]);
    }
    if (lane < 16) {
        const float* r3 = rhs3 + (size_t)bn * 16;
        const float* Eb = Et + b * 256;
        float s = 0.f;
#pragma unroll
        for (int tp = 0; tp < 16; ++tp) s += r3[tp] * Eb[tp * 16 + lane];
        rhs_sn[(size_t)bn * 16 + lane] = s;
    }
}

// grid: B*N*N/256 = 4096 blocks (b = gid>>18)
__global__ void k_sigT(const float* __restrict__ lhs_s, const float* __restrict__ rhs_sn,
                       const float* __restrict__ bsT, float* __restrict__ sigT) {
    int gid = blockIdx.x * 256 + threadIdx.x;
    int k = gid & 511, j = (gid >> 9) & 511, b = gid >> 18;
    const float4* lp = (const float4*)(lhs_s + (size_t)(b * 512 + k) * 16);
    const float4* rp = (const float4*)(rhs_sn + (size_t)(b * 512 + j) * 16);
    float s = 0.f;
#pragma unroll
    for (int q = 0; q < 4; ++q) {
        float4 a = lp[q], c = rp[q];
        s += a.x * c.x + a.y * c.y + a.z * c.z + a.w * c.w;
    }
    s += bsT[(size_t)j * 512 + k];
    sigT[gid] = 1.f / (1.f + expf(-s));
}

// S0T[b][j][i] = sum_k sigT[b][j][k] * Vs[i][k]
// LDS staged K-major [kk][68] -> b128 reads, compute-bound
__global__ __launch_bounds__(256) void k_gemm_s(const float* __restrict__ sigT,
                                                const float* __restrict__ Vs,
                                                float* __restrict__ S0T) {
    __shared__ float As[32 * 68];
    __shared__ float Bs[32 * 68];
    int bI = blockIdx.x, bJ = blockIdx.y, b = blockIdx.z;
    int tid = threadIdx.x, tx = tid & 15, ty = tid >> 4;
    float acc[4][4] = {};
    const float* Ab = sigT + ((size_t)b * 512 + bJ * 64) * 512;
    const float* Bb = Vs + (size_t)bI * 64 * 512;
    for (int k0 = 0; k0 < 512; k0 += 32) {
#pragma unroll
        for (int p = 0; p < 2; ++p) {
            int idx = tid + 256 * p;
            int row = idx >> 3, kk = (idx & 7) * 4;
            float4 a = *(const float4*)(Ab + (size_t)row * 512 + k0 + kk);
            As[(kk + 0) * 68 + row] = a.x; As[(kk + 1) * 68 + row] = a.y;
            As[(kk + 2) * 68 + row] = a.z; As[(kk + 3) * 68 + row] = a.w;
            float4 v = *(const float4*)(Bb + (size_t)row * 512 + k0 + kk);
            Bs[(kk + 0) * 68 + row] = v.x; Bs[(kk + 1) * 68 + row] = v.y;
            Bs[(kk + 2) * 68 + row] = v.z; Bs[(kk + 3) * 68 + row] = v.w;
        }
        __syncthreads();
#pragma unroll
        for (int kk = 0; kk < 32; ++kk) {
            float4 a = *(const float4*)(As + kk * 68 + ty * 4);
            float4 bv = *(const float4*)(Bs + kk * 68 + tx * 4);
            acc[0][0] += a.x * bv.x; acc[0][1] += a.x * bv.y; acc[0][2] += a.x * bv.z; acc[0][3] += a.x * bv.w;
            acc[1][0] += a.y * bv.x; acc[1][1] += a.y * bv.y; acc[1][2] += a.y * bv.z; acc[1][3] += a.y * bv.w;
            acc[2][0] += a.z * bv.x; acc[2][1] += a.z * bv.y; acc[2][2] += a.z * bv.z; acc[2][3] += a.z * bv.w;
            acc[3][0] += a.w * bv.x; acc[3][1] += a.w * bv.y; acc[3][2] += a.w * bv.z; acc[3][3] += a.w * bv.w;
        }
        __syncthreads();
    }
    float* Cb = S0T + ((size_t)b * 512 + bJ * 64) * 512 + bI * 64;
#pragma unroll
    for (int y = 0; y < 4; ++y) {
        int j = ty * 4 + y;
        *(float4*)(Cb + (size_t)j * 512 + tx * 4) =
            make_float4(acc[y][0], acc[y][1], acc[y][2], acc[y][3]);
    }
}

// softmax over i (contiguous) in-place; extract diagonal
__global__ void k_softmax_s(float* __restrict__ ST, float* __restrict__ diagS) {
    __shared__ float red[4];
    int bj = blockIdx.x;
    int b = bj >> 9, j = bj & 511;
    float* row = ST + (size_t)bj * 512;
    int tid = threadIdx.x;
    float v0 = row[tid], v1 = row[tid + 256];
    float m = fmaxf(v0, v1);
    for (int off = 32; off; off >>= 1) m = fmaxf(m, __shfl_xor(m, off));
    if ((tid & 63) == 0) red[tid >> 6] = m;
    __syncthreads();
    m = fmaxf(fmaxf(red[0], red[1]), fmaxf(red[2], red[3]));
    __syncthreads();
    float e0 = expf(v0 - m), e1 = expf(v1 - m);
    float s = e0 + e1;
    for (int off = 32; off; off >>= 1) s += __shfl_xor(s, off);
    if ((tid & 63) == 0) red[tid >> 6] = s;
    __syncthreads();
    s = red[0] + red[1] + red[2] + red[3];
    float inv = 1.f / s;
    float r0 = e0 * inv, r1 = e1 * inv;
    row[tid] = r0;
    row[tid + 256] = r1;
    if (j < 256) { if (tid == j) diagS[b * 512 + j] = r0; }
    else { if (tid == j - 256) diagS[b * 512 + j] = r1; }
}

// wS[b][pos] = csr_w[pos] * S[b,row,col] * diagS[b,col]
__global__ void k_wS(const int* __restrict__ csr_col, const int* __restrict__ csr_row,
                     const float* __restrict__ csr_w, const float* __restrict__ ST,
                     const float* __restrict__ diagS, float* __restrict__ wS) {
    int gid = blockIdx.x * 256 + threadIdx.x;
    int pos = gid & (NE - 1), b = gid >> 14;
    int c = csr_col[pos], r = csr_row[pos];
    wS[gid] = csr_w[pos] * ST[((size_t)(b * 512 + c)) * 512 + r] * diagS[b * 512 + c];
}

// Tx1[b,i,:,:] = sum_edges wS[b,p] * X[b,col,:,:]
__global__ __launch_bounds__(256) void k_prop1(const float* __restrict__ X,
                                               const float* __restrict__ wS,
                                               const int* __restrict__ csr_col,
                                               const int* __restrict__ row_start,
                                               float* __restrict__ Tx1) {
    int blk = ((blockIdx.x & 7) << 8) + (blockIdx.x >> 3);   // 2048 % 8 == 0
    int b = blk >> 9, i = blk & 511;
    int tid = threadIdx.x;
    int s = row_start[i], e2 = row_start[i + 1];
    const float4* Xb = (const float4*)(X + (size_t)b * 512 * 1024);
    const float* wb = wS + (size_t)b * NE;
    float4 acc = make_float4(0.f, 0.f, 0.f, 0.f);
    for (int p = s; p < e2; ++p) {
        int col = csr_col[p];
        float w = wb[p];
        float4 v = Xb[col * 256 + tid];
        acc.x += w * v.x; acc.y += w * v.y; acc.z += w * v.z; acc.w += w * v.w;
    }
    *(float4*)(Tx1 + (size_t)blk * 1024 + tid * 4) = acc;
}

// Tx2[b,i] = 2 * sum_edges csr_w[p]*Tx1[b,col] - diagS[b,i]*X[b,i]
__global__ __launch_bounds__(256) void k_prop2(const float* __restrict__ Tx1,
                                               const float* __restrict__ X,
                                               const float* __restrict__ diagS,
                                               const float* __restrict__ csr_w,
                                               const int* __restrict__ csr_col,
                                               const int* __restrict__ row_start,
                                               float* __restrict__ Tx2) {
    int blk = ((blockIdx.x & 7) << 8) + (blockIdx.x >> 3);
    int b = blk >> 9, i = blk & 511;
    int tid = threadIdx.x;
    int s = row_start[i], e2 = row_start[i + 1];
    const float4* T1b = (const float4*)(Tx1 + (size_t)b * 512 * 1024);
    float4 acc = make_float4(0.f, 0.f, 0.f, 0.f);
    for (int p = s; p < e2; ++p) {
        int col = csr_col[p];
        float w = csr_w[p];
        float4 v = T1b[col * 256 + tid];
        acc.x += w * v.x; acc.y += w * v.y; acc.z += w * v.z; acc.w += w * v.w;
    }
    float ds = diagS[blk];
    float4 x0 = *(const float4*)(X + (size_t)blk * 1024 + tid * 4);
    float4 o;
    o.x = 2.f * acc.x - ds * x0.x;
    o.y = 2.f * acc.y - ds * x0.y;
    o.z = 2.f * acc.z - ds * x0.z;
    o.w = 2.f * acc.w - ds * x0.w;
    *(float4*)(Tx2 + (size_t)blk * 1024 + tid * 4) = o;
}

// Xh[b,n,g,t] = relu(sum_f Wc[k][f][g]*Txk[b,n,f,t] + bc[g])
// 4 rows/block (wave per row); thread = 4g x 4t register tile
// g4 = (l&15)*4 spans g 0..63; t4 = (l>>4)*4 spans t 0..15   [round-6 bug fixed]
__global__ __launch_bounds__(256) void k_cheb(const float* __restrict__ X,
                                              const float* __restrict__ Tx1,
                                              const float* __restrict__ Tx2,
                                              const float* __restrict__ diagS,
                                              const float* __restrict__ Wc,
                                              const float* __restrict__ bc,
                                              float* __restrict__ Xh) {
    __shared__ float t0s[4][1024], t1s[4][1024], t2s[4][1024];
    int bn0 = blockIdx.x * 4;
    int tid = threadIdx.x;
    int r = tid >> 6, l = tid & 63;
    int bn = bn0 + r;
    float ds = diagS[bn];
    const float4* xp = (const float4*)(X + (size_t)bn * 1024);
    const float4* p1 = (const float4*)(Tx1 + (size_t)bn * 1024);
    const float4* p2 = (const float4*)(Tx2 + (size_t)bn * 1024);
#pragma unroll
    for (int k = 0; k < 4; ++k) {
        float4 v = xp[k * 64 + l];
        v.x *= ds; v.y *= ds; v.z *= ds; v.w *= ds;
        ((float4*)t0s[r])[k * 64 + l] = v;
        ((float4*)t1s[r])[k * 64 + l] = p1[k * 64 + l];
        ((float4*)t2s[r])[k * 64 + l] = p2[k * 64 + l];
    }
    __syncthreads();
    int g4 = (l & 15) * 4, t4 = (l >> 4) * 4;
    float4 bv = *(const float4*)(bc + g4);
    float4 acc0 = make_float4(bv.x, bv.x, bv.x, bv.x);
    float4 acc1 = make_float4(bv.y, bv.y, bv.y, bv.y);
    float4 acc2 = make_float4(bv.z, bv.z, bv.z, bv.z);
    float4 acc3 = make_float4(bv.w, bv.w, bv.w, bv.w);
    const float* t0r = t0s[r];
    const float* t1r = t1s[r];
    const float* t2r = t2s[r];
    for (int f = 0; f < 64; ++f) {
        float4 a0 = *(const float4*)(t0r + f * 16 + t4);
        float4 a1 = *(const float4*)(t1r + f * 16 + t4);
        float4 a2 = *(const float4*)(t2r + f * 16 + t4);
        float4 w0 = *(const float4*)(Wc + f * 64 + g4);
        float4 w1 = *(const float4*)(Wc + 4096 + f * 64 + g4);
        float4 w2 = *(const float4*)(Wc + 8192 + f * 64 + g4);
        acc0.x += w0.x * a0.x + w1.x * a1.x + w2.x * a2.x;
        acc0.y += w0.x * a0.y + w1.x * a1.y + w2.x * a2.y;
        acc0.z += w0.x * a0.z + w1.x * a1.z + w2.x * a2.z;
        acc0.w += w0.x * a0.w + w1.x * a1.w + w2.x * a2.w;
        acc1.x += w0.y * a0.x + w1.y * a1.x + w2.y * a2.x;
        acc1.y += w0.y * a0.y + w1.y * a1.y + w2.y * a2.y;
        acc1.z += w0.y * a0.z + w1.y * a1.z + w2.y * a2.z;
        acc1.w += w0.y * a0.w + w1.y * a1.w + w2.y * a2.w;
        acc2.x += w0.z * a0.x + w1.z * a1.x + w2.z * a2.x;
        acc2.y += w0.z * a0.y + w1.z * a1.y + w2.z * a2.y;
        acc2.z += w0.z * a0.z + w1.z * a1.z + w2.z * a2.z;
        acc2.w += w0.z * a0.w + w1.z * a1.w + w2.z * a2.w;
        acc3.x += w0.w * a0.x + w1.w * a1.x + w2.w * a2.x;
        acc3.y += w0.w * a0.y + w1.w * a1.y + w2.w * a2.y;
        acc3.z += w0.w * a0.z + w1.w * a1.z + w2.w * a2.z;
        acc3.w += w0.w * a0.w + w1.w * a1.w + w2.w * a2.w;
    }
    float* op = Xh + (size_t)bn * 1024;
    float4 o0, o1, o2, o3;
    o0.x = fmaxf(acc0.x, 0.f); o0.y = fmaxf(acc0.y, 0.f); o0.z = fmaxf(acc0.z, 0.f); o0.w = fmaxf(acc0.w, 0.f);
    o1.x = fmaxf(acc1.x, 0.f); o1.y = fmaxf(acc1.y, 0.f); o1.z = fmaxf(acc1.z, 0.f); o1.w = fmaxf(acc1.w, 0.f);
    o2.x = fmaxf(acc2.x, 0.f); o2.y = fmaxf(acc2.y, 0.f); o2.z = fmaxf(acc2.z, 0.f); o2.w = fmaxf(acc2.w, 0.f);
    o3.x = fmaxf(acc3.x, 0.f); o3.y = fmaxf(acc3.y, 0.f); o3.z = fmaxf(acc3.z, 0.f); o3.w = fmaxf(acc3.w, 0.f);
    *(float4*)(op + (g4 + 0) * 16 + t4) = o0;
    *(float4*)(op + (g4 + 1) * 16 + t4) = o1;
    *(float4*)(op + (g4 + 2) * 16 + t4) = o2;
    *(float4*)(op + (g4 + 3) * 16 + t4) = o3;
}

// fused time-conv + residual conv + relu + LayerNorm + output transpose
__global__ __launch_bounds__(256) void k_out(const float* __restrict__ X,
                                             const float* __restrict__ Xh,
                                             const float* __restrict__ WtT,
                                             const float* __restrict__ WrT,
                                             const float* __restrict__ bt,
                                             const float* __restrict__ br,
                                             const float* __restrict__ gamma,
                                             const float* __restrict__ beta,
                                             float* __restrict__ out) {
    __shared__ float xh[64 * 20];   // [g][slot], slot = t+1, slots 0,17..19 zero
    __shared__ float xl[64 * 16];   // [f][t]
    __shared__ float red[4160];     // 4*16*64 partials; reused as z[t*65+o]
    int bn = blockIdx.x;
    int tid = threadIdx.x;
    int o = tid & 63, q = tid >> 6;
    {
        int g = tid & 63, s4 = tid >> 6;
        int slot = (s4 == 0) ? 0 : 16 + s4;   // 0,17,18,19
        xh[g * 20 + slot] = 0.f;
    }
    {
        float4 v = ((const float4*)(Xh + (size_t)bn * 1024))[tid];
        int g = tid >> 2, t0 = (tid & 3) * 4;
        xh[g * 20 + t0 + 1] = v.x;
        xh[g * 20 + t0 + 2] = v.y;
        xh[g * 20 + t0 + 3] = v.z;
        xh[g * 20 + t0 + 4] = v.w;
        float4 u = ((const float4*)(X + (size_t)bn * 1024))[tid];
        *(float4*)(xl + tid * 4) = u;
    }
    __syncthreads();
    float acc[16];
#pragma unroll
    for (int k = 0; k < 16; ++k) acc[k] = 0.f;
    for (int gi = 0; gi < 16; ++gi) {
        int g = q * 16 + gi;
        const float4* xp = (const float4*)(xh + g * 20);
        float4 xa = xp[0], xb = xp[1], xc = xp[2], xd = xp[3], xe = xp[4];
        float xs[20] = {xa.x, xa.y, xa.z, xa.w, xb.x, xb.y, xb.z, xb.w,
                        xc.x, xc.y, xc.z, xc.w, xd.x, xd.y, xd.z, xd.w,
                        xe.x, xe.y, xe.z, xe.w};
        float w0 = WtT[(g * 3 + 0) * 64 + o];
        float w1 = WtT[(g * 3 + 1) * 64 + o];
        float w2 = WtT[(g * 3 + 2) * 64 + o];
#pragma unroll
        for (int tt = 0; tt < 16; ++tt)
            acc[tt] += xs[tt] * w0 + xs[tt + 1] * w1 + xs[tt + 2] * w2;
    }
    for (int fi = 0; fi < 16; ++fi) {
        int f = q * 16 + fi;
        const float4* xp = (const float4*)(xl + f * 16);
        float4 xa = xp[0], xb = xp[1], xc = xp[2], xd = xp[3];
        float xs[16] = {xa.x, xa.y, xa.z, xa.w, xb.x, xb.y, xb.z, xb.w,
                        xc.x, xc.y, xc.z, xc.w, xd.x, xd.y, xd.z, xd.w};
        float w = WrT[f * 64 + o];
#pragma unroll
        for (int tt = 0; tt < 16; ++tt) acc[tt] += xs[tt] * w;
    }
#pragma unroll
    for (int tt = 0; tt < 16; ++tt) red[q * 1024 + tt * 64 + o] = acc[tt];
    __syncthreads();
    float bsum = bt[o] + br[o];
    float go = gamma[o], bo = beta[o];
    float zv4[4];
#pragma unroll
    for (int tt = 0; tt < 4; ++tt) {
        int t = q * 4 + tt;
        float s = bsum;
#pragma unroll
        for (int qq = 0; qq < 4; ++qq) s += red[qq * 1024 + t * 64 + o];
        zv4[tt] = fmaxf(s, 0.f);
    }
    __syncthreads();
#pragma unroll
    for (int tt = 0; tt < 4; ++tt) {
        int t = q * 4 + tt;
        float zv = zv4[tt];
        float s = zv, sq = zv * zv;
        for (int off = 32; off; off >>= 1) {
            s += __shfl_xor(s, off);
            sq += __shfl_xor(sq, off);
        }
        float mu = s * (1.f / 64.f);
        float var = sq * (1.f / 64.f) - mu * mu;
        red[t * 65 + o] = (zv - mu) * rsqrtf(var + 1e-5f) * go + bo;
    }
    __syncthreads();
#pragma unroll
    for (int k = 0; k < 4; ++k) {
        int i = tid + 256 * k;               // i = o*16 + t
        out[(size_t)bn * 1024 + i] = red[(i & 15) * 65 + (i >> 4)];
    }
}

extern "C" void kernel_launch(void* const* d_in, const int* in_sizes, int n_in,
                              void* d_out, int out_size, void* d_ws, size_t ws_size,
                              hipStream_t stream) {
    const float* X     = (const float*)d_in[0];
    const int*   ei    = (const int*)d_in[1];
    const float* U1    = (const float*)d_in[2];
    const float* U2    = (const float*)d_in[3];
    const float* U3    = (const float*)d_in[4];
    const float* be    = (const float*)d_in[5];
    const float* Ve    = (const float*)d_in[6];
    const float* Ws1   = (const float*)d_in[7];
    const float* Ws2   = (const float*)d_in[8];
    const float* Ws3   = (const float*)d_in[9];
    const float* bs    = (const float*)d_in[10];
    const float* Vs    = (const float*)d_in[11];
    const float* Wc    = (const float*)d_in[12];
    const float* bc    = (const float*)d_in[13];
    const float* Wt    = (const float*)d_in[14];
    const float* bt    = (const float*)d_in[15];
    const float* Wr    = (const float*)d_in[16];
    const float* br    = (const float*)d_in[17];
    const float* gamma = (const float*)d_in[18];
    const float* beta  = (const float*)d_in[19];

    float* ws = (float*)d_ws;
    float* Tx1    = ws + TX1_OFF;
    float* Tx2    = ws + TX2_OFF;
    float* Xh     = ws + XHAT_OFF;
    float* ST     = ws + ST_OFF;     // shares TX1 (dead before k_prop1)
    float* sigT   = ws + SIGT_OFF;   // shares TX2 (dead before k_prop2)
    float* bsT    = ws + BST_OFF;
    float* Et     = ws + ET_OFF;
    float* part   = ws + PART_OFF;
    float* rhs_t  = ws + RHST_OFF;
    float* lhs_s  = ws + LHSS_OFF;
    float* rhs_sn = ws + RHSSN_OFF;
    float* diagS  = ws + DIAGS_OFF;
    float* wS     = ws + WSATT_OFF;
    float* csr_w  = ws + CSRW_OFF;
    float* WtT    = ws + WTT_OFF;
    float* WrT    = ws + WRT_OFF;
    float* dis    = ws + DIS_OFF;
    float* rhs3   = ws + RHS3_OFF;
    float* ew1    = ws + EW1_OFF;

    int* ib        = (int*)(ws + FEND);
    int* row_start = ib;                  // 513 (pad to 516)
    int* csr_col   = ib + 516;            // NE
    int* csr_row   = csr_col + NE;        // NE
    int* counts    = csr_row + NE;        // 64*512

    // graph prep (parallel, deterministic)
    k_hist<<<64, 256, 0, stream>>>(ei, counts);
    k_scan2<<<1, 512, 0, stream>>>(counts, dis, row_start);
    k_fill2<<<64, 256, 0, stream>>>(ei, counts, row_start, dis, csr_col, csr_row, csr_w);

    // weight transposes (independent)
    k_wprep<<<64, 256, 0, stream>>>(Wt, Wr, WtT, WrT);
    k_bst<<<dim3(8, 8), 256, 0, stream>>>(bs, bsT);

    // temporal attention
    k_lhs1_partial<<<32, 256, 0, stream>>>(X, U1, part);
    k_rhs_t<<<128, 256, 0, stream>>>(X, U3, Ws3, rhs_t, rhs3);
    k_temporal<<<4, 256, 0, stream>>>(part, rhs_t, U2, be, Ve, Ws1, Et, ew1);

    // spatial attention (Xt eliminated algebraically)
    k_spat2<<<512, 256, 0, stream>>>(X, ew1, rhs3, Et, Ws2, lhs_s, rhs_sn);
    k_sigT<<<4096, 256, 0, stream>>>(lhs_s, rhs_sn, bsT, sigT);
    k_gemm_s<<<dim3(8, 8, 4), 256, 0, stream>>>(sigT, Vs, ST);
    k_softmax_s<<<2048, 256, 0, stream>>>(ST, diagS);
    k_wS<<<256, 256, 0, stream>>>(csr_col, csr_row, csr_w, ST, diagS, wS);

    // chebyshev conv (B,N,F,T layout)
    k_prop1<<<2048, 256, 0, stream>>>(X, wS, csr_col, row_start, Tx1);
    k_prop2<<<2048, 256, 0, stream>>>(Tx1, X, diagS, csr_w, csr_col, row_start, Tx2);
    k_cheb<<<512, 256, 0, stream>>>(X, Tx1, Tx2, diagS, Wc, bc, Xh);

    // time conv + residual + LN + transpose
    k_out<<<2048, 256, 0, stream>>>(X, Xh, WtT, WrT, bt, br, gamma, beta, (float*)d_out);
}